// Round 3
// baseline (777.705 us; speedup 1.0000x reference)
//
#include <hip/hip_runtime.h>
#include <hip/hip_bf16.h>

// ---------------------------------------------------------------------------
// Generator_58737972740271: encoder (lin+BN+ReLU x2, lin+sigmoid), 4 relation
// blocks rewritten via associativity  (x x^T)U == x (x^T U),  decoder + heads.
// Runtime dtype detection (fp32 vs bf16 external I/O); fp32 compute; bf16
// intermediates in ws. Workspace budget: 18.5 MB.
// ---------------------------------------------------------------------------

typedef __hip_bfloat16 bf16;

#define NB 32
#define NN 1024

// flag-aware external load (d_in buffers): f32 ? float : bf16
__device__ __forceinline__ float ldin(const void* p, size_t i, int f32){
    return f32 ? ((const float*)p)[i] : __bfloat162float(((const bf16*)p)[i]);
}
__device__ __forceinline__ float ld_bf16(const bf16* p, size_t i){
    return __bfloat162float(p[i]);
}
__device__ __forceinline__ void st_bf16(bf16* p, size_t i, float v){
    p[i] = __float2bfloat16(v);
}

// ---------------- dtype detector -------------------------------------------
// input is uniform[0,1): non-negative. bf16 pair in a 32b word -> bits 15 and
// 31 are bf16 sign bits == 0. fp32 word -> bit15 is a random mantissa bit.
__global__ __launch_bounds__(64) void k_detect(const void* __restrict__ inp, int* __restrict__ flag){
    int t = threadIdx.x;
    unsigned v = ((const unsigned*)inp)[t];
    int hit = (v & 0x80008000u) ? 1 : 0;
    unsigned long long m = __ballot(hit);
    if (t == 0) *flag = (__popcll(m) > 4) ? 1 : 0;   // 1 = fp32 external
}

// ---------------- prep: weights -> fp32 [K][O] -----------------------------
struct PrepArgs {
    const void* w[11];
    int K[11], O[11], off[11];
};

__global__ __launch_bounds__(256) void k_prep(PrepArgs a, float* __restrict__ pool,
                                              const int* __restrict__ flag){
    int f32 = *flag;
    int s = blockIdx.y;
    int K = a.K[s], O = a.O[s];
    int idx = blockIdx.x*256 + threadIdx.x;
    if (idx >= K*O) return;
    int k = idx / O, j = idx - k*O;
    pool[a.off[s] + idx] = ldin(a.w[s], (size_t)j*K + k, f32);   // W[j,k] -> wt[k][j]
}

// ---------------- fused linear + BatchNorm(channel=n) + ReLU ---------------
// one wave per n: all 32 x O outputs for that n live in the wave's registers.
template<int K, int O, bool EXTIN>
__global__ __launch_bounds__(128) void k_bnlin(
    const void* __restrict__ xin, const float* __restrict__ Wt,
    const void* __restrict__ bias, const void* __restrict__ bng,
    const void* __restrict__ bnb, bf16* __restrict__ out,
    const int* __restrict__ flag)
{
    int f32 = *flag;
    constexpr int BR  = O/16;    // rows (b) per thread
    constexpr int NBT = 32/BR;   // b tiles
    __shared__ __align__(16) float wt[K*O];
    __shared__ __align__(16) float xst[2][K*36];   // [k][b], pad 36
    int t = threadIdx.x;
    int w = t >> 6, lane = t & 63;
    int n = blockIdx.x*2 + w;

    for (int i = t; i < K*O; i += 128) wt[i] = Wt[i];
    for (int i = lane; i < 32*K; i += 64){
        int b = i / K, k = i - b*K;
        float v;
        if (EXTIN) v = ldin(xin, ((size_t)b*NN + n)*K + k, f32);
        else       v = ld_bf16((const bf16*)xin, ((size_t)b*NN + n)*K + k);
        xst[w][k*36 + b] = v;
    }
    __syncthreads();

    int bt = lane % NBT, jt = lane / NBT;
    int b0 = bt*BR, j0 = jt*8;
    const float* xw = xst[w];
    float acc[BR][8];
    #pragma unroll
    for (int i=0;i<BR;i++)
        #pragma unroll
        for (int j=0;j<8;j++) acc[i][j] = 0.f;

    for (int k = 0; k < K; k++){
        float xv[BR], wv[8];
        #pragma unroll
        for (int i=0;i<BR;i+=4)
            *reinterpret_cast<float4*>(&xv[i]) = *reinterpret_cast<const float4*>(&xw[k*36 + b0 + i]);
        *reinterpret_cast<float4*>(&wv[0]) = *reinterpret_cast<const float4*>(&wt[k*O + j0]);
        *reinterpret_cast<float4*>(&wv[4]) = *reinterpret_cast<const float4*>(&wt[k*O + j0 + 4]);
        #pragma unroll
        for (int i=0;i<BR;i++)
            #pragma unroll
            for (int j=0;j<8;j++) acc[i][j] = fmaf(xv[i], wv[j], acc[i][j]);
    }

    float bj[8];
    #pragma unroll
    for (int j=0;j<8;j++) bj[j] = ldin(bias, j0+j, f32);
    float s1 = 0.f, s2 = 0.f;
    #pragma unroll
    for (int i=0;i<BR;i++)
        #pragma unroll
        for (int j=0;j<8;j++){
            float a = acc[i][j] + bj[j];
            acc[i][j] = a; s1 += a; s2 = fmaf(a, a, s2);
        }
    #pragma unroll
    for (int off = 32; off > 0; off >>= 1){
        s1 += __shfl_down(s1, off);
        s2 += __shfl_down(s2, off);
    }
    s1 = __shfl(s1, 0); s2 = __shfl(s2, 0);
    const float M = 32.f * O;
    float m  = s1 / M;
    float vv = s2 / M - m*m;
    float rs = rsqrtf(vv + 1e-5f);
    float gv = ldin(bng, n, f32), bv = ldin(bnb, n, f32);
    #pragma unroll
    for (int i=0;i<BR;i++)
        #pragma unroll
        for (int j=0;j<8;j++){
            float o = fmaxf(fmaf(gv*(acc[i][j]-m), rs, bv), 0.f);
            st_bf16(out, ((size_t)(b0+i)*NN + n)*O + j0 + j, o);
        }
}

// ---------------- 128->128 linear. MODE 0: sigmoid. MODE 1: relu + d -------
template<int MODE>
__global__ __launch_bounds__(256) void k_lin128(
    const bf16* __restrict__ xin, const float* __restrict__ Wt,
    const void* __restrict__ bias, bf16* __restrict__ out, float* __restrict__ dvec,
    const int* __restrict__ flag)
{
    int f32 = *flag;
    __shared__ __align__(16) float wt[128*128];
    __shared__ __align__(16) float xst[128*68];     // [k][r], 64 rows, pad 68
    int t = threadIdx.x;
    size_t row0 = (size_t)blockIdx.x * 64;
    for (int i = t; i < 128*128; i += 256) wt[i] = Wt[i];
    for (int i = t; i < 64*128; i += 256){
        int r = i >> 7, k = i & 127;
        xst[k*68 + r] = ld_bf16(xin, (row0 + r)*128 + k);
    }
    __syncthreads();

    int rt = t & 15, ct = t >> 4;
    int r0 = rt*4, c0 = ct*8;
    float acc[4][8] = {};
    #pragma unroll 4
    for (int k = 0; k < 128; k++){
        float xv[4], wv[8];
        *reinterpret_cast<float4*>(&xv[0]) = *reinterpret_cast<const float4*>(&xst[k*68 + r0]);
        *reinterpret_cast<float4*>(&wv[0]) = *reinterpret_cast<const float4*>(&wt[k*128 + c0]);
        *reinterpret_cast<float4*>(&wv[4]) = *reinterpret_cast<const float4*>(&wt[k*128 + c0 + 4]);
        #pragma unroll
        for (int i=0;i<4;i++)
            #pragma unroll
            for (int j=0;j<8;j++) acc[i][j] = fmaf(xv[i], wv[j], acc[i][j]);
    }
    float bj[8];
    #pragma unroll
    for (int j=0;j<8;j++) bj[j] = ldin(bias, c0+j, f32);
    #pragma unroll
    for (int i=0;i<4;i++)
        #pragma unroll
        for (int j=0;j<8;j++){
            float a = acc[i][j] + bj[j];
            float o = (MODE==0) ? 1.f/(1.f+expf(-a)) : fmaxf(a, 0.f);
            st_bf16(out, (row0 + r0 + i)*128 + c0 + j, o);
        }
    if (MODE==1 && t < 64){
        float s = 0.f;
        #pragma unroll 8
        for (int k=0;k<128;k++){ float v = xst[k*68 + t]; s = fmaf(v, v, s); }
        dvec[row0 + t] = s;
    }
}

// ---------------- T = x^T U per batch, column-split (no partials) ----------
__global__ __launch_bounds__(256) void k_relT2(
    const bf16* __restrict__ x, const bf16* __restrict__ U, float* __restrict__ T)
{
    int b  = blockIdx.x;
    int ks = blockIdx.y * 32;
    __shared__ __align__(16) float us[64*128];
    __shared__ __align__(16) float xs[64*36];
    int t = threadIdx.x;
    int tc = t & 31, tk = t >> 5;
    float acc[4][4] = {};
    const bf16* xb = x + (size_t)b*NN*128;
    const bf16* ub = U + (size_t)b*NN*128;
    for (int chunk = 0; chunk < 16; chunk++){
        __syncthreads();
        int r0 = chunk*64;
        for (int i = t; i < 64*128; i += 256) us[i] = ld_bf16(ub, (size_t)r0*128 + i);
        for (int i = t; i < 64*32; i += 256){
            int r = i >> 5, k = i & 31;
            xs[r*36 + k] = ld_bf16(xb, (size_t)(r0 + r)*128 + ks + k);
        }
        __syncthreads();
        for (int r = 0; r < 64; r++){
            float xv[4], uv[4];
            *reinterpret_cast<float4*>(xv) = *reinterpret_cast<const float4*>(&xs[r*36 + tk*4]);
            *reinterpret_cast<float4*>(uv) = *reinterpret_cast<const float4*>(&us[r*128 + tc*4]);
            #pragma unroll
            for (int p=0;p<4;p++)
                #pragma unroll
                for (int q=0;q<4;q++) acc[p][q] = fmaf(xv[p], uv[q], acc[p][q]);
        }
    }
    float* dst = T + (size_t)b*16384;
    #pragma unroll
    for (int p=0;p<4;p++)
        *reinterpret_cast<float4*>(&dst[(ks + tk*4 + p)*128 + tc*4]) =
            *reinterpret_cast<float4*>(&acc[p][0]);
}

// ---------------- out_i = alpha*(x_i @ T - d_i*U_i) + x_i  (in place) ------
__global__ __launch_bounds__(256) void k_relout(
    bf16* __restrict__ x, const bf16* __restrict__ U, const float* __restrict__ T,
    const float* __restrict__ dvec,
    const void* __restrict__ psi, const void* __restrict__ phi, const void* __restrict__ wr,
    const int* __restrict__ flag)
{
    int f32 = *flag;
    __shared__ __align__(16) float ts[128*128];
    __shared__ __align__(16) float xst[128*68];
    int t = threadIdx.x;
    size_t row0 = (size_t)blockIdx.x * 64;
    int batch = (int)(row0 >> 10);
    const float* Tb = T + (size_t)batch*16384;
    for (int i = t; i < 16384; i += 256) ts[i] = Tb[i];
    for (int i = t; i < 64*128; i += 256){
        int r = i >> 7, k = i & 127;
        xst[k*68 + r] = ld_bf16(x, (row0 + r)*128 + k);
    }
    __syncthreads();
    float alpha = ldin(wr,0,f32) * ldin(psi,0,f32) * ldin(phi,0,f32) * (1.f/1024.f);
    int rt = t & 15, ct = t >> 4;
    int r0 = rt*4, c0 = ct*8;
    float acc[4][8] = {};
    #pragma unroll 4
    for (int k = 0; k < 128; k++){
        float xv[4], wv[8];
        *reinterpret_cast<float4*>(&xv[0]) = *reinterpret_cast<const float4*>(&xst[k*68 + r0]);
        *reinterpret_cast<float4*>(&wv[0]) = *reinterpret_cast<const float4*>(&ts[k*128 + c0]);
        *reinterpret_cast<float4*>(&wv[4]) = *reinterpret_cast<const float4*>(&ts[k*128 + c0 + 4]);
        #pragma unroll
        for (int i=0;i<4;i++)
            #pragma unroll
            for (int j=0;j<8;j++) acc[i][j] = fmaf(xv[i], wv[j], acc[i][j]);
    }
    #pragma unroll
    for (int i=0;i<4;i++){
        int r = r0 + i;
        float dr = dvec[row0 + r];
        #pragma unroll
        for (int j=0;j<8;j++){
            float uv = ld_bf16(U, (row0 + r)*128 + c0 + j);
            float xc = xst[(c0+j)*68 + r];
            st_bf16(x, (row0 + r)*128 + c0 + j, fmaf(alpha, acc[i][j] - dr*uv, xc));
        }
    }
}

// ---------------- decoder tail: relu(lin 64->32) + two heads + concat ------
__global__ __launch_bounds__(256) void k_dec2(
    const bf16* __restrict__ x,           // [B,N,64]
    const float* __restrict__ W2t,        // [64][32]
    const void* __restrict__ b2,
    const float* __restrict__ Wct,        // [32][28]
    const void* __restrict__ bcb,
    const float* __restrict__ Wgt,        // [32][4]
    const void* __restrict__ bgb,
    void* __restrict__ out,               // [B,N,32] flag dtype
    const int* __restrict__ flag)
{
    int f32 = *flag;
    __shared__ __align__(16) float w2[64*32];
    __shared__ __align__(16) float wc[32*28];
    __shared__ __align__(16) float wg[32*4];
    __shared__ __align__(16) float xs[8][64];
    __shared__ float hs[8][33];
    size_t row0 = (size_t)blockIdx.x * 8;
    int t = threadIdx.x;
    for (int i=t;i<64*32;i+=256) w2[i]=W2t[i];
    for (int i=t;i<32*28;i+=256) wc[i]=Wct[i];
    for (int i=t;i<32*4;i+=256)  wg[i]=Wgt[i];
    for (int i=t;i<8*64;i+=256)  xs[i>>6][i&63] = ld_bf16(x, (row0 + (i>>6))*64 + (i&63));
    __syncthreads();
    int j = t & 31, r = t >> 5;
    float a = ldin(b2, j, f32);
    #pragma unroll 8
    for (int k=0;k<64;k++) a = fmaf(xs[r][k], w2[k*32 + j], a);
    hs[r][j] = fmaxf(a, 0.f);
    __syncthreads();
    float o;
    if (j < 28){
        o = ldin(bcb, j, f32);
        #pragma unroll
        for (int k=0;k<32;k++) o = fmaf(hs[r][k], wc[k*28 + j], o);
    } else {
        int jj = j - 28;
        o = ldin(bgb, jj, f32);
        #pragma unroll
        for (int k=0;k<32;k++) o = fmaf(hs[r][k], wg[k*4 + jj], o);
    }
    size_t oi = (row0 + r)*32 + j;
    if (f32) ((float*)out)[oi] = o;
    else     ((bf16*)out)[oi] = __float2bfloat16(o);
}

// ---------------------------------------------------------------------------
extern "C" void kernel_launch(void* const* d_in, const int* in_sizes, int n_in,
                              void* d_out, int out_size, void* d_ws, size_t ws_size,
                              hipStream_t stream)
{
    (void)in_sizes; (void)n_in; (void)out_size; (void)ws_size;
    const void* input = d_in[0];
    const void* e1_W = d_in[1];  const void* e1_b = d_in[2];
    const void* bn1_g = d_in[3]; const void* bn1_b = d_in[4];
    const void* e2_W = d_in[5];  const void* e2_b = d_in[6];
    const void* bn2_g = d_in[7]; const void* bn2_b = d_in[8];
    const void* e3_W = d_in[9];  const void* e3_b = d_in[10];
    const void *rW[4], *rb[4], *rpsi[4], *rphi[4], *rwr[4];
    for (int r = 0; r < 4; r++){
        rW[r]   = d_in[11 + r*5 + 0];
        rb[r]   = d_in[11 + r*5 + 1];
        rpsi[r] = d_in[11 + r*5 + 2];
        rphi[r] = d_in[11 + r*5 + 3];
        rwr[r]  = d_in[11 + r*5 + 4];
    }
    const void* d1_W = d_in[31]; const void* d1_b = d_in[32];
    const void* dbn_g = d_in[33];const void* dbn_b = d_in[34];
    const void* d2_W = d_in[35]; const void* d2_b = d_in[36];
    const void* bc_W = d_in[37]; const void* bc_b = d_in[38];
    const void* bg_W = d_in[39]; const void* bg_b = d_in[40];

    // ---- workspace layout (18.5 MB total), small fixed arrays first ----
    float* ws_f = (float*)d_ws;
    int*   flag = (int*)d_ws;                      // [0..64) reserved
    float* wp   = ws_f + 64;                       // 103,424 fp32
    float* dd   = ws_f + 103552;                   // 32,768 fp32
    float* T    = ws_f + 136448;                   // 524,288 fp32
    bf16*  A    = (bf16*)(ws_f + 660736);          // [32768][128] bf16 (8 MB)
    bf16*  U    = (bf16*)(ws_f + 660736 + 2097152);// [32768][128] bf16 (8 MB)
    bf16*  Cenc = A;                               // [32768][64] overlays A (dead)
    bf16*  Cdec = U;                               // [32768][64] overlays U (dead)

    enum { O_E1=0, O_E2=2048, O_E3=10240, O_R1=26624, O_R2=43008, O_R3=59392,
           O_R4=75776, O_D1=92160, O_D2=100352, O_BC=102400, O_BG=103296 };

    PrepArgs pa;
    const void* srcs[11] = {e1_W, e2_W, e3_W, rW[0], rW[1], rW[2], rW[3], d1_W, d2_W, bc_W, bg_W};
    const int  Ks[11]   = {32,64,128,128,128,128,128,128,64,32,32};
    const int  Os[11]   = {64,128,128,128,128,128,128,64,32,28,4};
    const int  offs[11] = {O_E1,O_E2,O_E3,O_R1,O_R2,O_R3,O_R4,O_D1,O_D2,O_BC,O_BG};
    for (int i=0;i<11;i++){ pa.w[i]=srcs[i]; pa.K[i]=Ks[i]; pa.O[i]=Os[i]; pa.off[i]=offs[i]; }

    k_detect<<<1, 64, 0, stream>>>(input, flag);
    k_prep<<<dim3(64,11), 256, 0, stream>>>(pa, wp, flag);
    k_bnlin<32,64,true><<<512, 128, 0, stream>>>(input, wp+O_E1, e1_b, bn1_g, bn1_b, Cenc, flag);
    k_bnlin<64,128,false><<<512, 128, 0, stream>>>(Cenc, wp+O_E2, e2_b, bn2_g, bn2_b, U, flag);
    k_lin128<0><<<512, 256, 0, stream>>>(U, wp+O_E3, e3_b, A, (float*)nullptr, flag);

    const int ro[4] = {O_R1, O_R2, O_R3, O_R4};
    for (int r = 0; r < 4; r++){
        k_lin128<1><<<512, 256, 0, stream>>>(A, wp+ro[r], rb[r], U, dd, flag);
        k_relT2<<<dim3(32,4), 256, 0, stream>>>(A, U, T);
        k_relout<<<512, 256, 0, stream>>>(A, U, T, dd, rpsi[r], rphi[r], rwr[r], flag);
    }

    k_bnlin<128,64,false><<<512, 128, 0, stream>>>(A, wp+O_D1, d1_b, dbn_g, dbn_b, Cdec, flag);
    k_dec2<<<4096, 256, 0, stream>>>(Cdec, wp+O_D2, d2_b, wp+O_BC, bc_b, wp+O_BG, bg_b, d_out, flag);
}

// Round 4
// 455.411 us; speedup vs baseline: 1.7077x; 1.7077x over previous
//
#include <hip/hip_runtime.h>
#include <hip/hip_bf16.h>

// ---------------------------------------------------------------------------
// Generator_58737972740271: encoder (lin+BN+ReLU x2, lin+sigmoid), 4 relation
// blocks rewritten via associativity  (x x^T)U == x (x^T U),  decoder + heads.
// Runtime dtype detection (fp32 vs bf16 external I/O); fp32 compute; bf16
// intermediates. R4: vectorized bf16 staging everywhere, k_relT split-K with
// fp32 partials (512 blocks), 2-blocks/CU tiling for the 128-wide GEMMs.
// Workspace: 27.8 MB.
// ---------------------------------------------------------------------------

typedef __hip_bfloat16 bf16;

#define NB 32
#define NN 1024

__device__ __forceinline__ float ldin(const void* p, size_t i, int f32){
    return f32 ? ((const float*)p)[i] : __bfloat162float(((const bf16*)p)[i]);
}
__device__ __forceinline__ float ld_bf16(const bf16* p, size_t i){
    return __bfloat162float(p[i]);
}
__device__ __forceinline__ unsigned short f2bf(float v){
    bf16 h = __float2bfloat16(v);
    unsigned short s; __builtin_memcpy(&s, &h, 2);
    return s;
}
__device__ __forceinline__ void unpack8(uint4 v, float* f){
    f[0] = __uint_as_float(v.x << 16);
    f[1] = __uint_as_float(v.x & 0xffff0000u);
    f[2] = __uint_as_float(v.y << 16);
    f[3] = __uint_as_float(v.y & 0xffff0000u);
    f[4] = __uint_as_float(v.z << 16);
    f[5] = __uint_as_float(v.z & 0xffff0000u);
    f[6] = __uint_as_float(v.w << 16);
    f[7] = __uint_as_float(v.w & 0xffff0000u);
}

// ---------------- dtype detector -------------------------------------------
__global__ __launch_bounds__(64) void k_detect(const void* __restrict__ inp, int* __restrict__ flag){
    int t = threadIdx.x;
    unsigned v = ((const unsigned*)inp)[t];
    int hit = (v & 0x80008000u) ? 1 : 0;
    unsigned long long m = __ballot(hit);
    if (t == 0) *flag = (__popcll(m) > 4) ? 1 : 0;   // 1 = fp32 external
}

// ---------------- prep: weights -> fp32 [K][O] -----------------------------
struct PrepArgs {
    const void* w[11];
    int K[11], O[11], off[11];
};

__global__ __launch_bounds__(256) void k_prep(PrepArgs a, float* __restrict__ pool,
                                              const int* __restrict__ flag){
    int f32 = *flag;
    int s = blockIdx.y;
    int K = a.K[s], O = a.O[s];
    int idx = blockIdx.x*256 + threadIdx.x;
    if (idx >= K*O) return;
    int k = idx / O, j = idx - k*O;
    pool[a.off[s] + idx] = ldin(a.w[s], (size_t)j*K + k, f32);   // W[j,k] -> wt[k][j]
}

// ---------------- fused linear + BatchNorm(channel=n) + ReLU ---------------
template<int K, int O, bool EXTIN>
__global__ __launch_bounds__(128) void k_bnlin(
    const void* __restrict__ xin, const float* __restrict__ Wt,
    const void* __restrict__ bias, const void* __restrict__ bng,
    const void* __restrict__ bnb, bf16* __restrict__ out,
    const int* __restrict__ flag)
{
    int f32 = *flag;
    constexpr int BR  = O/16;
    constexpr int NBT = 32/BR;
    constexpr int G   = K/8;
    __shared__ __align__(16) float wt[K*O];
    __shared__ __align__(16) float xst[2][K*36];
    int t = threadIdx.x;
    int w = t >> 6, lane = t & 63;
    int n = blockIdx.x*2 + w;

    for (int i = t; i < K*O/4; i += 128)
        reinterpret_cast<float4*>(wt)[i] = reinterpret_cast<const float4*>(Wt)[i];
    for (int i = lane; i < 32*G; i += 64){
        int b = i / G, g = i - b*G;
        float f[8];
        if (EXTIN && f32){
            const float* src = (const float*)xin + ((size_t)b*NN + n)*K + g*8;
            float4 v0 = *reinterpret_cast<const float4*>(src);
            float4 v1 = *reinterpret_cast<const float4*>(src + 4);
            f[0]=v0.x; f[1]=v0.y; f[2]=v0.z; f[3]=v0.w;
            f[4]=v1.x; f[5]=v1.y; f[6]=v1.z; f[7]=v1.w;
        } else {
            uint4 v = *reinterpret_cast<const uint4*>((const bf16*)xin + ((size_t)b*NN + n)*K + g*8);
            unpack8(v, f);
        }
        #pragma unroll
        for (int j=0;j<8;j++) xst[w][(g*8+j)*36 + b] = f[j];
    }
    __syncthreads();

    int bt = lane % NBT, jt = lane / NBT;
    int b0 = bt*BR, j0 = jt*8;
    const float* xw = xst[w];
    float acc[BR][8];
    #pragma unroll
    for (int i=0;i<BR;i++)
        #pragma unroll
        for (int j=0;j<8;j++) acc[i][j] = 0.f;

    for (int k = 0; k < K; k++){
        float xv[BR], wv[8];
        #pragma unroll
        for (int i=0;i<BR;i+=4)
            *reinterpret_cast<float4*>(&xv[i]) = *reinterpret_cast<const float4*>(&xw[k*36 + b0 + i]);
        *reinterpret_cast<float4*>(&wv[0]) = *reinterpret_cast<const float4*>(&wt[k*O + j0]);
        *reinterpret_cast<float4*>(&wv[4]) = *reinterpret_cast<const float4*>(&wt[k*O + j0 + 4]);
        #pragma unroll
        for (int i=0;i<BR;i++)
            #pragma unroll
            for (int j=0;j<8;j++) acc[i][j] = fmaf(xv[i], wv[j], acc[i][j]);
    }

    float bj[8];
    #pragma unroll
    for (int j=0;j<8;j++) bj[j] = ldin(bias, j0+j, f32);
    float s1 = 0.f, s2 = 0.f;
    #pragma unroll
    for (int i=0;i<BR;i++)
        #pragma unroll
        for (int j=0;j<8;j++){
            float a = acc[i][j] + bj[j];
            acc[i][j] = a; s1 += a; s2 = fmaf(a, a, s2);
        }
    #pragma unroll
    for (int off = 32; off > 0; off >>= 1){
        s1 += __shfl_down(s1, off);
        s2 += __shfl_down(s2, off);
    }
    s1 = __shfl(s1, 0); s2 = __shfl(s2, 0);
    const float M = 32.f * O;
    float m  = s1 / M;
    float vv = s2 / M - m*m;
    float rs = rsqrtf(vv + 1e-5f);
    float gv = ldin(bng, n, f32), bv = ldin(bnb, n, f32);
    #pragma unroll
    for (int i=0;i<BR;i++){
        union { uint4 u; unsigned short s[8]; } pk;
        #pragma unroll
        for (int j=0;j<8;j++)
            pk.s[j] = f2bf(fmaxf(fmaf(gv*(acc[i][j]-m), rs, bv), 0.f));
        *reinterpret_cast<uint4*>(out + ((size_t)(b0+i)*NN + n)*O + j0) = pk.u;
    }
}

// ---------------- 128->128 linear, 64x64 tiles. MODE0 sigmoid, MODE1 relu+d
template<int MODE>
__global__ __launch_bounds__(256) void k_lin128(
    const bf16* __restrict__ xin, const float* __restrict__ Wt,
    const void* __restrict__ bias, bf16* __restrict__ out, float* __restrict__ dvec,
    const int* __restrict__ flag)
{
    int f32 = *flag;
    __shared__ __align__(16) float wt[128*64];     // 32 KB
    __shared__ __align__(16) float xst[128*68];    // 34.8 KB
    int t = threadIdx.x;
    size_t row0 = (size_t)blockIdx.x * 64;
    int cs = blockIdx.y;                            // column half
    #pragma unroll
    for (int c = 0; c < 8; c++){
        int i = t + c*256;                          // 2048 float4 groups
        int k = i >> 4, g = i & 15;
        *reinterpret_cast<float4*>(&wt[k*64 + g*4]) =
            *reinterpret_cast<const float4*>(&Wt[k*128 + cs*64 + g*4]);
    }
    #pragma unroll
    for (int c = 0; c < 4; c++){
        int i = t + c*256;                          // 1024 uint4 groups
        int r = i & 63, kg = i >> 6;
        uint4 v = *reinterpret_cast<const uint4*>(xin + (row0 + r)*128 + kg*8);
        float f[8]; unpack8(v, f);
        #pragma unroll
        for (int j=0;j<8;j++) xst[(kg*8+j)*68 + r] = f[j];
    }
    __syncthreads();

    int rt = t & 15, ct = t >> 4;
    int r0 = rt*4, c0 = ct*4;
    float acc[4][4] = {};
    #pragma unroll 4
    for (int k = 0; k < 128; k++){
        float xv[4], wv[4];
        *reinterpret_cast<float4*>(xv) = *reinterpret_cast<const float4*>(&xst[k*68 + r0]);
        *reinterpret_cast<float4*>(wv) = *reinterpret_cast<const float4*>(&wt[k*64 + c0]);
        #pragma unroll
        for (int i=0;i<4;i++)
            #pragma unroll
            for (int j=0;j<4;j++) acc[i][j] = fmaf(xv[i], wv[j], acc[i][j]);
    }
    float bj[4];
    #pragma unroll
    for (int j=0;j<4;j++) bj[j] = ldin(bias, cs*64 + c0 + j, f32);
    #pragma unroll
    for (int i=0;i<4;i++){
        union { uint2 u; unsigned short s[4]; } pk;
        #pragma unroll
        for (int j=0;j<4;j++){
            float a = acc[i][j] + bj[j];
            pk.s[j] = f2bf((MODE==0) ? 1.f/(1.f+expf(-a)) : fmaxf(a, 0.f));
        }
        *reinterpret_cast<uint2*>(out + (row0 + r0 + i)*128 + cs*64 + c0) = pk.u;
    }
    if (MODE==1 && cs==0 && t < 64){
        float s = 0.f;
        #pragma unroll 8
        for (int k=0;k<128;k++){ float v = xst[k*68 + t]; s = fmaf(v, v, s); }
        dvec[row0 + t] = s;
    }
}

// ---------------- T = x^T U per batch, split-K partials --------------------
// grid (32, 16): rs = K-chunk of 256 rows, cs = T-row slice of 32.
__global__ __launch_bounds__(256) void k_relT3(
    const bf16* __restrict__ x, const bf16* __restrict__ U, float* __restrict__ Tp)
{
    int b  = blockIdx.x;
    int rs = blockIdx.y & 3;
    int cs = blockIdx.y >> 2;
    __shared__ __align__(16) float us[64*128];   // 32 KB
    __shared__ __align__(16) float xs[64*36];    // 9 KB
    int t = threadIdx.x;
    int tc = t & 31, tk = t >> 5;
    float acc[4][4] = {};
    const bf16* xb = x + ((size_t)b*NN + rs*256)*128 + cs*32;
    const bf16* ub = U + ((size_t)b*NN + rs*256)*128;
    for (int chunk = 0; chunk < 4; chunk++){
        __syncthreads();
        const uint4* usrc = reinterpret_cast<const uint4*>(ub + (size_t)chunk*64*128);
        #pragma unroll
        for (int c = 0; c < 4; c++){
            int i = t + c*256;                   // 1024 uint4 groups
            uint4 v = usrc[i];
            float f[8]; unpack8(v, f);
            int base = (i >> 4)*128 + (i & 15)*8;
            *reinterpret_cast<float4*>(&us[base])   = make_float4(f[0],f[1],f[2],f[3]);
            *reinterpret_cast<float4*>(&us[base+4]) = make_float4(f[4],f[5],f[6],f[7]);
        }
        {
            int row = t >> 2, seg = t & 3;       // 256 uint4 groups
            uint4 v = *reinterpret_cast<const uint4*>(xb + ((size_t)chunk*64 + row)*128 + seg*8);
            float f[8]; unpack8(v, f);
            int base = row*36 + seg*8;
            *reinterpret_cast<float4*>(&xs[base])   = make_float4(f[0],f[1],f[2],f[3]);
            *reinterpret_cast<float4*>(&xs[base+4]) = make_float4(f[4],f[5],f[6],f[7]);
        }
        __syncthreads();
        #pragma unroll 2
        for (int r = 0; r < 64; r++){
            float xv[4], uv[4];
            *reinterpret_cast<float4*>(xv) = *reinterpret_cast<const float4*>(&xs[r*36 + tk*4]);
            *reinterpret_cast<float4*>(uv) = *reinterpret_cast<const float4*>(&us[r*128 + tc*4]);
            #pragma unroll
            for (int p=0;p<4;p++)
                #pragma unroll
                for (int q=0;q<4;q++) acc[p][q] = fmaf(xv[p], uv[q], acc[p][q]);
        }
    }
    float* dst = Tp + ((size_t)rs*NB + b)*16384;
    #pragma unroll
    for (int p=0;p<4;p++)
        *reinterpret_cast<float4*>(&dst[(cs*32 + tk*4 + p)*128 + tc*4]) =
            *reinterpret_cast<float4*>(&acc[p][0]);
}

__global__ __launch_bounds__(256) void k_tred(const float* __restrict__ Tp, float* __restrict__ T){
    int idx = blockIdx.x*256 + threadIdx.x;      // 524288 total
    T[idx] = (Tp[idx] + Tp[524288 + idx]) + (Tp[1048576 + idx] + Tp[1572864 + idx]);
}

// ---------------- out_i = alpha*(x_i @ T - d_i*U_i) + x_i  (in place) ------
// Each block owns 64 rows; processes both column halves sequentially so the
// in-place write stays race-free. LDS 66.8 KB -> 2 blocks/CU.
__global__ __launch_bounds__(256) void k_relout(
    bf16* __restrict__ x, const bf16* __restrict__ U, const float* __restrict__ T,
    const float* __restrict__ dvec,
    const void* __restrict__ psi, const void* __restrict__ phi, const void* __restrict__ wr,
    const int* __restrict__ flag)
{
    int f32 = *flag;
    __shared__ __align__(16) float ts[128*64];   // 32 KB
    __shared__ __align__(16) float xst[128*68];  // 34.8 KB
    int t = threadIdx.x;
    size_t row0 = (size_t)blockIdx.x * 64;
    int batch = (int)(row0 >> 10);
    const float* Tb = T + (size_t)batch*16384;
    #pragma unroll
    for (int c = 0; c < 4; c++){
        int i = t + c*256;
        int r = i & 63, kg = i >> 6;
        uint4 v = *reinterpret_cast<const uint4*>(x + (row0 + r)*128 + kg*8);
        float f[8]; unpack8(v, f);
        #pragma unroll
        for (int j=0;j<8;j++) xst[(kg*8+j)*68 + r] = f[j];
    }
    float alpha = ldin(wr,0,f32) * ldin(psi,0,f32) * ldin(phi,0,f32) * (1.f/1024.f);
    int rt = t & 15, ct = t >> 4;
    int r0 = rt*4, c0 = ct*4;
    for (int cs = 0; cs < 2; cs++){
        __syncthreads();
        #pragma unroll
        for (int c = 0; c < 8; c++){
            int i = t + c*256;
            int k = i >> 4, g = i & 15;
            *reinterpret_cast<float4*>(&ts[k*64 + g*4]) =
                *reinterpret_cast<const float4*>(&Tb[k*128 + cs*64 + g*4]);
        }
        __syncthreads();
        float acc[4][4] = {};
        #pragma unroll 4
        for (int k = 0; k < 128; k++){
            float xv[4], wv[4];
            *reinterpret_cast<float4*>(xv) = *reinterpret_cast<const float4*>(&xst[k*68 + r0]);
            *reinterpret_cast<float4*>(wv) = *reinterpret_cast<const float4*>(&ts[k*64 + c0]);
            #pragma unroll
            for (int i=0;i<4;i++)
                #pragma unroll
                for (int j=0;j<4;j++) acc[i][j] = fmaf(xv[i], wv[j], acc[i][j]);
        }
        #pragma unroll
        for (int i=0;i<4;i++){
            int r = r0 + i;
            float dr = dvec[row0 + r];
            uint2 uu = *reinterpret_cast<const uint2*>(U + (row0 + r)*128 + cs*64 + c0);
            float uf[4];
            uf[0]=__uint_as_float(uu.x<<16); uf[1]=__uint_as_float(uu.x&0xffff0000u);
            uf[2]=__uint_as_float(uu.y<<16); uf[3]=__uint_as_float(uu.y&0xffff0000u);
            union { uint2 u; unsigned short s[4]; } pk;
            #pragma unroll
            for (int j=0;j<4;j++){
                float xc = xst[(cs*64 + c0 + j)*68 + r];
                pk.s[j] = f2bf(fmaf(alpha, acc[i][j] - dr*uf[j], xc));
            }
            *reinterpret_cast<uint2*>(x + (row0 + r)*128 + cs*64 + c0) = pk.u;
        }
    }
}

// ---------------- decoder tail: relu(lin 64->32) + two heads + concat ------
__global__ __launch_bounds__(256) void k_dec2(
    const bf16* __restrict__ x,           // [B,N,64]
    const float* __restrict__ W2t, const void* __restrict__ b2,
    const float* __restrict__ Wct, const void* __restrict__ bcb,
    const float* __restrict__ Wgt, const void* __restrict__ bgb,
    void* __restrict__ out, const int* __restrict__ flag)
{
    int f32 = *flag;
    __shared__ __align__(16) float w2[64*32];
    __shared__ __align__(16) float wc[32*28];
    __shared__ __align__(16) float wg[32*4];
    __shared__ __align__(16) float xs[8][64];
    __shared__ float hs[8][33];
    size_t row0 = (size_t)blockIdx.x * 8;
    int t = threadIdx.x;
    for (int i=t;i<512;i+=256)  reinterpret_cast<float4*>(w2)[i] = reinterpret_cast<const float4*>(W2t)[i];
    if (t < 224) reinterpret_cast<float4*>(wc)[t] = reinterpret_cast<const float4*>(Wct)[t];
    if (t < 32)  reinterpret_cast<float4*>(wg)[t] = reinterpret_cast<const float4*>(Wgt)[t];
    if (t < 64){
        int row = t >> 3, seg = t & 7;
        uint4 v = *reinterpret_cast<const uint4*>(x + (row0 + row)*64 + seg*8);
        float f[8]; unpack8(v, f);
        *reinterpret_cast<float4*>(&xs[row][seg*8])   = make_float4(f[0],f[1],f[2],f[3]);
        *reinterpret_cast<float4*>(&xs[row][seg*8+4]) = make_float4(f[4],f[5],f[6],f[7]);
    }
    __syncthreads();
    int j = t & 31, r = t >> 5;
    float a = ldin(b2, j, f32);
    #pragma unroll 8
    for (int k=0;k<64;k++) a = fmaf(xs[r][k], w2[k*32 + j], a);
    hs[r][j] = fmaxf(a, 0.f);
    __syncthreads();
    float o;
    if (j < 28){
        o = ldin(bcb, j, f32);
        #pragma unroll
        for (int k=0;k<32;k++) o = fmaf(hs[r][k], wc[k*28 + j], o);
    } else {
        int jj = j - 28;
        o = ldin(bgb, jj, f32);
        #pragma unroll
        for (int k=0;k<32;k++) o = fmaf(hs[r][k], wg[k*4 + jj], o);
    }
    size_t oi = (row0 + r)*32 + j;
    if (f32) ((float*)out)[oi] = o;
    else     ((bf16*)out)[oi] = __float2bfloat16(o);
}

// ---------------------------------------------------------------------------
extern "C" void kernel_launch(void* const* d_in, const int* in_sizes, int n_in,
                              void* d_out, int out_size, void* d_ws, size_t ws_size,
                              hipStream_t stream)
{
    (void)in_sizes; (void)n_in; (void)out_size; (void)ws_size;
    const void* input = d_in[0];
    const void* e1_W = d_in[1];  const void* e1_b = d_in[2];
    const void* bn1_g = d_in[3]; const void* bn1_b = d_in[4];
    const void* e2_W = d_in[5];  const void* e2_b = d_in[6];
    const void* bn2_g = d_in[7]; const void* bn2_b = d_in[8];
    const void* e3_W = d_in[9];  const void* e3_b = d_in[10];
    const void *rW[4], *rb[4], *rpsi[4], *rphi[4], *rwr[4];
    for (int r = 0; r < 4; r++){
        rW[r]   = d_in[11 + r*5 + 0];
        rb[r]   = d_in[11 + r*5 + 1];
        rpsi[r] = d_in[11 + r*5 + 2];
        rphi[r] = d_in[11 + r*5 + 3];
        rwr[r]  = d_in[11 + r*5 + 4];
    }
    const void* d1_W = d_in[31]; const void* d1_b = d_in[32];
    const void* dbn_g = d_in[33];const void* dbn_b = d_in[34];
    const void* d2_W = d_in[35]; const void* d2_b = d_in[36];
    const void* bc_W = d_in[37]; const void* bc_b = d_in[38];
    const void* bg_W = d_in[39]; const void* bg_b = d_in[40];

    // ---- workspace layout (27.8 MB) ----
    float* ws_f = (float*)d_ws;
    int*   flag = (int*)d_ws;                       // 64 floats reserved
    float* wp   = ws_f + 64;                        // 103,424
    float* dd   = ws_f + 103552;                    // 32,768
    float* T    = ws_f + 136448;                    // 524,288 (2 MB)
    float* Tp   = ws_f + 660736;                    // 2,097,152 (8.4 MB)
    bf16*  A    = (bf16*)(ws_f + 2757888);          // [32768][128] bf16 (8 MB)
    bf16*  U    = (bf16*)(ws_f + 4855040);          // [32768][128] bf16 (8 MB)
    bf16*  Cenc = A;                                // [32768][64] overlays A
    bf16*  Cdec = U;                                // [32768][64] overlays U

    enum { O_E1=0, O_E2=2048, O_E3=10240, O_R1=26624, O_R2=43008, O_R3=59392,
           O_R4=75776, O_D1=92160, O_D2=100352, O_BC=102400, O_BG=103296 };

    PrepArgs pa;
    const void* srcs[11] = {e1_W, e2_W, e3_W, rW[0], rW[1], rW[2], rW[3], d1_W, d2_W, bc_W, bg_W};
    const int  Ks[11]   = {32,64,128,128,128,128,128,128,64,32,32};
    const int  Os[11]   = {64,128,128,128,128,128,128,64,32,28,4};
    const int  offs[11] = {O_E1,O_E2,O_E3,O_R1,O_R2,O_R3,O_R4,O_D1,O_D2,O_BC,O_BG};
    for (int i=0;i<11;i++){ pa.w[i]=srcs[i]; pa.K[i]=Ks[i]; pa.O[i]=Os[i]; pa.off[i]=offs[i]; }

    k_detect<<<1, 64, 0, stream>>>(input, flag);
    k_prep<<<dim3(64,11), 256, 0, stream>>>(pa, wp, flag);
    k_bnlin<32,64,true><<<512, 128, 0, stream>>>(input, wp+O_E1, e1_b, bn1_g, bn1_b, Cenc, flag);
    k_bnlin<64,128,false><<<512, 128, 0, stream>>>(Cenc, wp+O_E2, e2_b, bn2_g, bn2_b, U, flag);
    k_lin128<0><<<dim3(512,2), 256, 0, stream>>>(U, wp+O_E3, e3_b, A, (float*)nullptr, flag);

    const int ro[4] = {O_R1, O_R2, O_R3, O_R4};
    for (int r = 0; r < 4; r++){
        k_lin128<1><<<dim3(512,2), 256, 0, stream>>>(A, wp+ro[r], rb[r], U, dd, flag);
        k_relT3<<<dim3(32,16), 256, 0, stream>>>(A, U, Tp);
        k_tred<<<2048, 256, 0, stream>>>(Tp, T);
        k_relout<<<512, 256, 0, stream>>>(A, U, T, dd, rpsi[r], rphi[r], rwr[r], flag);
    }

    k_bnlin<128,64,false><<<512, 128, 0, stream>>>(A, wp+O_D1, d1_b, dbn_g, dbn_b, Cdec, flag);
    k_dec2<<<4096, 256, 0, stream>>>(Cdec, wp+O_D2, d2_b, wp+O_BC, bc_b, wp+O_BG, bg_b, d_out, flag);
}

// Round 5
// 374.187 us; speedup vs baseline: 2.0784x; 1.2171x over previous
//
#include <hip/hip_runtime.h>
#include <hip/hip_bf16.h>

// ---------------------------------------------------------------------------
// Generator_58737972740271.  R5: MFMA (bf16 16x16x32) for the three 128-wide
// GEMM families.  fp32-origin operands (weights, T) are split hi/lo bf16 and
// fed through two MFMA chains to keep fp32-like precision.  Activations bf16
// (unchanged vs R4).  LDS fragment layout: k-group-major [k>>3][row][8] so
// fragments are single ds_read_b128 with <=2-way bank aliasing.
// ---------------------------------------------------------------------------

typedef __hip_bfloat16 bf16;
typedef unsigned short ushort_t;
typedef float v4f __attribute__((ext_vector_type(4)));
typedef short v8s __attribute__((ext_vector_type(8)));
#define MFMA_BF16 __builtin_amdgcn_mfma_f32_16x16x32_bf16

#define NB 32
#define NN 1024

__device__ __forceinline__ float ldin(const void* p, size_t i, int f32){
    return f32 ? ((const float*)p)[i] : __bfloat162float(((const bf16*)p)[i]);
}
__device__ __forceinline__ float bf2f(ushort_t u){
    return __uint_as_float((unsigned)u << 16);
}
__device__ __forceinline__ ushort_t f2bf(float v){
    bf16 h = __float2bfloat16(v);
    ushort_t s; __builtin_memcpy(&s, &h, 2);
    return s;
}
__device__ __forceinline__ void unpack8(uint4 v, float* f){
    f[0] = __uint_as_float(v.x << 16);
    f[1] = __uint_as_float(v.x & 0xffff0000u);
    f[2] = __uint_as_float(v.y << 16);
    f[3] = __uint_as_float(v.y & 0xffff0000u);
    f[4] = __uint_as_float(v.z << 16);
    f[5] = __uint_as_float(v.z & 0xffff0000u);
    f[6] = __uint_as_float(v.w << 16);
    f[7] = __uint_as_float(v.w & 0xffff0000u);
}

// ---------------- dtype detector -------------------------------------------
__global__ __launch_bounds__(64) void k_detect(const void* __restrict__ inp, int* __restrict__ flag){
    int t = threadIdx.x;
    unsigned v = ((const unsigned*)inp)[t];
    int hit = (v & 0x80008000u) ? 1 : 0;
    unsigned long long m = __ballot(hit);
    if (t == 0) *flag = (__popcll(m) > 4) ? 1 : 0;   // 1 = fp32 external
}

// ---------------- prep -----------------------------------------------------
// slabs 0..5: fp32 [K][O] transposed weights (bnlin/dec2).
// slabs 6..10: 128x128 weights -> hi/lo bf16, MFMA-B layout [k>>3][n][k&7].
struct PrepArgs {
    const void* w[11];
    int K[11], O[11], off[11];
};

__global__ __launch_bounds__(256) void k_prep(PrepArgs a, float* __restrict__ wpf,
                                              ushort_t* __restrict__ whi, ushort_t* __restrict__ wlo,
                                              const int* __restrict__ flag){
    int f32 = *flag;
    int s = blockIdx.y;
    int idx = blockIdx.x*256 + threadIdx.x;
    if (s < 6){
        int K = a.K[s], O = a.O[s];
        if (idx >= K*O) return;
        int k = idx / O, j = idx - k*O;
        wpf[a.off[s] + idx] = ldin(a.w[s], (size_t)j*K + k, f32);   // W[j,k] -> wt[k][j]
    } else {
        if (idx >= 16384) return;
        int n = idx >> 7, k = idx & 127;
        float v = ldin(a.w[s], (size_t)n*128 + k, f32);
        ushort_t h = f2bf(v);
        ushort_t l = f2bf(v - bf2f(h));
        int di = (s - 6)*16384 + ((k >> 3)*128 + n)*8 + (k & 7);
        whi[di] = h; wlo[di] = l;
    }
}

// ---------------- fused linear + BatchNorm(channel=n) + ReLU (VALU) --------
template<int K, int O, bool EXTIN>
__global__ __launch_bounds__(128) void k_bnlin(
    const void* __restrict__ xin, const float* __restrict__ Wt,
    const void* __restrict__ bias, const void* __restrict__ bng,
    const void* __restrict__ bnb, bf16* __restrict__ out,
    const int* __restrict__ flag)
{
    int f32 = *flag;
    constexpr int BR  = O/16;
    constexpr int NBT = 32/BR;
    constexpr int G   = K/8;
    __shared__ __align__(16) float wt[K*O];
    __shared__ __align__(16) float xst[2][K*36];
    int t = threadIdx.x;
    int w = t >> 6, lane = t & 63;
    int n = blockIdx.x*2 + w;

    for (int i = t; i < K*O/4; i += 128)
        reinterpret_cast<float4*>(wt)[i] = reinterpret_cast<const float4*>(Wt)[i];
    for (int i = lane; i < 32*G; i += 64){
        int b = i / G, g = i - b*G;
        float f[8];
        if (EXTIN && f32){
            const float* src = (const float*)xin + ((size_t)b*NN + n)*K + g*8;
            float4 v0 = *reinterpret_cast<const float4*>(src);
            float4 v1 = *reinterpret_cast<const float4*>(src + 4);
            f[0]=v0.x; f[1]=v0.y; f[2]=v0.z; f[3]=v0.w;
            f[4]=v1.x; f[5]=v1.y; f[6]=v1.z; f[7]=v1.w;
        } else {
            uint4 v = *reinterpret_cast<const uint4*>((const bf16*)xin + ((size_t)b*NN + n)*K + g*8);
            unpack8(v, f);
        }
        #pragma unroll
        for (int j=0;j<8;j++) xst[w][(g*8+j)*36 + b] = f[j];
    }
    __syncthreads();

    int bt = lane % NBT, jt = lane / NBT;
    int b0 = bt*BR, j0 = jt*8;
    const float* xw = xst[w];
    float acc[BR][8];
    #pragma unroll
    for (int i=0;i<BR;i++)
        #pragma unroll
        for (int j=0;j<8;j++) acc[i][j] = 0.f;

    for (int k = 0; k < K; k++){
        float xv[BR], wv[8];
        #pragma unroll
        for (int i=0;i<BR;i+=4)
            *reinterpret_cast<float4*>(&xv[i]) = *reinterpret_cast<const float4*>(&xw[k*36 + b0 + i]);
        *reinterpret_cast<float4*>(&wv[0]) = *reinterpret_cast<const float4*>(&wt[k*O + j0]);
        *reinterpret_cast<float4*>(&wv[4]) = *reinterpret_cast<const float4*>(&wt[k*O + j0 + 4]);
        #pragma unroll
        for (int i=0;i<BR;i++)
            #pragma unroll
            for (int j=0;j<8;j++) acc[i][j] = fmaf(xv[i], wv[j], acc[i][j]);
    }

    float bj[8];
    #pragma unroll
    for (int j=0;j<8;j++) bj[j] = ldin(bias, j0+j, f32);
    float s1 = 0.f, s2 = 0.f;
    #pragma unroll
    for (int i=0;i<BR;i++)
        #pragma unroll
        for (int j=0;j<8;j++){
            float a = acc[i][j] + bj[j];
            acc[i][j] = a; s1 += a; s2 = fmaf(a, a, s2);
        }
    #pragma unroll
    for (int off = 32; off > 0; off >>= 1){
        s1 += __shfl_down(s1, off);
        s2 += __shfl_down(s2, off);
    }
    s1 = __shfl(s1, 0); s2 = __shfl(s2, 0);
    const float M = 32.f * O;
    float m  = s1 / M;
    float vv = s2 / M - m*m;
    float rs = rsqrtf(vv + 1e-5f);
    float gv = ldin(bng, n, f32), bv = ldin(bnb, n, f32);
    #pragma unroll
    for (int i=0;i<BR;i++){
        union { uint4 u; ushort_t s[8]; } pk;
        #pragma unroll
        for (int j=0;j<8;j++)
            pk.s[j] = f2bf(fmaxf(fmaf(gv*(acc[i][j]-m), rs, bv), 0.f));
        *reinterpret_cast<uint4*>(out + ((size_t)(b0+i)*NN + n)*O + j0) = pk.u;
    }
}

// ---------------- MFMA 128->128 linear -------------------------------------
// block = 64 rows x 128 cols, 4 waves (wave = 64r x 32n).  W hi/lo bf16.
// MODE 0: sigmoid -> outA row-major.  MODE 1: relu -> outUT [b][n][r] + dvec.
template<int MODE>
__global__ __launch_bounds__(256) void k_lin128m(
    const ushort_t* __restrict__ xin,                    // row-major [32768][128]
    const ushort_t* __restrict__ Whi, const ushort_t* __restrict__ Wlo,
    const void* __restrict__ bias,
    ushort_t* __restrict__ outA, ushort_t* __restrict__ outUT,
    float* __restrict__ dvec, const int* __restrict__ flag)
{
    __shared__ ushort_t xs[16384];   // [k>>3][r][8]   16 KB
    __shared__ ushort_t wh[16384];   // [k>>3][n][8]   32 KB
    __shared__ ushort_t wl[16384];
    int t = threadIdx.x;
    size_t row0 = (size_t)blockIdx.x * 64;
    {
        const uint4* src = reinterpret_cast<const uint4*>(xin + row0*128);
        #pragma unroll
        for (int c = 0; c < 4; c++){
            int i = t + c*256;
            int r = i >> 4, kg = i & 15;
            *reinterpret_cast<uint4*>(&xs[(kg*64 + r)*8]) = src[i];
        }
        const uint4* sh = reinterpret_cast<const uint4*>(Whi);
        const uint4* sl = reinterpret_cast<const uint4*>(Wlo);
        #pragma unroll
        for (int c = 0; c < 8; c++){
            int i = t + c*256;
            reinterpret_cast<uint4*>(wh)[i] = sh[i];
            reinterpret_cast<uint4*>(wl)[i] = sl[i];
        }
    }
    __syncthreads();
    int w = t >> 6, lane = t & 63;
    int col = lane & 15, quad = lane >> 4;
    v4f acc[4][2];
    #pragma unroll
    for (int m=0;m<4;m++)
        #pragma unroll
        for (int nt=0;nt<2;nt++) acc[m][nt] = (v4f){0.f,0.f,0.f,0.f};

    #pragma unroll
    for (int kt = 0; kt < 4; kt++){
        int kg = kt*4 + quad;
        v8s a[4], bh[2], bl[2];
        #pragma unroll
        for (int m=0;m<4;m++)
            a[m] = *reinterpret_cast<const v8s*>(&xs[(kg*64 + m*16 + col)*8]);
        #pragma unroll
        for (int nt=0;nt<2;nt++){
            int n = w*32 + nt*16 + col;
            bh[nt] = *reinterpret_cast<const v8s*>(&wh[(kg*128 + n)*8]);
            bl[nt] = *reinterpret_cast<const v8s*>(&wl[(kg*128 + n)*8]);
        }
        #pragma unroll
        for (int m=0;m<4;m++)
            #pragma unroll
            for (int nt=0;nt<2;nt++){
                acc[m][nt] = MFMA_BF16(a[m], bh[nt], acc[m][nt], 0, 0, 0);
                acc[m][nt] = MFMA_BF16(a[m], bl[nt], acc[m][nt], 0, 0, 0);
            }
    }
    int f32 = *flag;
    int b = (int)(row0 >> 10);
    int rbase = (int)(row0 & 1023);
    #pragma unroll
    for (int nt=0;nt<2;nt++){
        int n = w*32 + nt*16 + col;
        float bn = ldin(bias, n, f32);
        #pragma unroll
        for (int m=0;m<4;m++){
            if (MODE == 0){
                #pragma unroll
                for (int reg=0;reg<4;reg++){
                    int r = m*16 + quad*4 + reg;
                    float v = acc[m][nt][reg] + bn;
                    outA[(row0 + r)*128 + n] = f2bf(1.f/(1.f+expf(-v)));
                }
            } else {
                union { uint2 u; ushort_t s[4]; } pk;
                #pragma unroll
                for (int reg=0;reg<4;reg++)
                    pk.s[reg] = f2bf(fmaxf(acc[m][nt][reg] + bn, 0.f));
                int rb = rbase + m*16 + quad*4;
                *reinterpret_cast<uint2*>(&outUT[((size_t)b*128 + n)*1024 + rb]) = pk.u;
            }
        }
    }
    if (MODE == 1 && t < 64){
        float s = 0.f;
        #pragma unroll 8
        for (int k=0;k<128;k++){
            float v = bf2f(xs[((k>>3)*64 + t)*8 + (k&7)]);
            s = fmaf(v, v, s);
        }
        dvec[row0 + t] = s;
    }
}

// ---------------- MFMA  Tt = (x^T U)^T = U^T x,  split-K x8 ----------------
// grid (32 b, 8 rs).  Block: full 128(n) x 128(c) tile over 128 rows.
// A = U^T from UT global (direct stage), B = x^T (scatter stage).
__global__ __launch_bounds__(256) void k_relTm(
    const ushort_t* __restrict__ x,   // row-major [32768][128]
    const ushort_t* __restrict__ UT,  // [32][128][1024]
    float* __restrict__ Tp)           // [8][32][128][128]
{
    __shared__ ushort_t uts[8192];    // [r>>3][n][8]  (64 r per chunk) 16 KB
    __shared__ ushort_t xts[8192];    // [r>>3][c][8]                  16 KB
    int b = blockIdx.x, rs = blockIdx.y;
    int t = threadIdx.x;
    int w = t >> 6, lane = t & 63;
    int col = lane & 15, quad = lane >> 4;
    int wn = (w >> 1)*64, wc = (w & 1)*64;
    v4f acc[4][4];
    #pragma unroll
    for (int m=0;m<4;m++)
        #pragma unroll
        for (int q=0;q<4;q++) acc[m][q] = (v4f){0.f,0.f,0.f,0.f};

    for (int ch = 0; ch < 2; ch++){
        __syncthreads();
        int r0 = rs*128 + ch*64;
        #pragma unroll
        for (int c = 0; c < 4; c++){           // UT direct: [n][64 r]
            int i = t + c*256;
            int n = i >> 3, rg = i & 7;
            *reinterpret_cast<uint4*>(&uts[(rg*128 + n)*8]) =
                *reinterpret_cast<const uint4*>(&UT[((size_t)b*128 + n)*1024 + r0 + rg*8]);
        }
        #pragma unroll
        for (int c = 0; c < 4; c++){           // x scatter-transpose
            int i = t + c*256;
            int r = i >> 4, cs8 = (i & 15)*8;
            uint4 v = *reinterpret_cast<const uint4*>(&x[((size_t)b*1024 + r0 + r)*128 + cs8]);
            int base = ((r >> 3)*128 + cs8)*8 + (r & 7);
            xts[base     ] = (ushort_t)(v.x & 0xffff);
            xts[base + 8 ] = (ushort_t)(v.x >> 16);
            xts[base + 16] = (ushort_t)(v.y & 0xffff);
            xts[base + 24] = (ushort_t)(v.y >> 16);
            xts[base + 32] = (ushort_t)(v.z & 0xffff);
            xts[base + 40] = (ushort_t)(v.z >> 16);
            xts[base + 48] = (ushort_t)(v.w & 0xffff);
            xts[base + 56] = (ushort_t)(v.w >> 16);
        }
        __syncthreads();
        #pragma unroll
        for (int kt = 0; kt < 2; kt++){
            int kg = kt*4 + quad;
            v8s a[4], bb[4];
            #pragma unroll
            for (int m=0;m<4;m++)
                a[m] = *reinterpret_cast<const v8s*>(&uts[(kg*128 + wn + m*16 + col)*8]);
            #pragma unroll
            for (int q=0;q<4;q++)
                bb[q] = *reinterpret_cast<const v8s*>(&xts[(kg*128 + wc + q*16 + col)*8]);
            #pragma unroll
            for (int m=0;m<4;m++)
                #pragma unroll
                for (int q=0;q<4;q++)
                    acc[m][q] = MFMA_BF16(a[m], bb[q], acc[m][q], 0, 0, 0);
        }
    }
    float* dst = Tp + (((size_t)rs*NB + b) << 14);
    #pragma unroll
    for (int m=0;m<4;m++)
        #pragma unroll
        for (int q=0;q<4;q++)
            #pragma unroll
            for (int reg=0;reg<4;reg++){
                int n = wn + m*16 + quad*4 + reg;
                int c = wc + q*16 + col;
                dst[n*128 + c] = acc[m][q][reg];
            }
}

// ---------------- reduce partials -> Tt hi/lo bf16 -------------------------
__global__ __launch_bounds__(256) void k_tredm(const float* __restrict__ Tp,
                                               ushort_t* __restrict__ Thi, ushort_t* __restrict__ Tlo){
    int i = blockIdx.x*256 + threadIdx.x;        // 524288 total
    const size_t S = 524288;
    float s = ((Tp[i] + Tp[S+i]) + (Tp[2*S+i] + Tp[3*S+i]))
            + ((Tp[4*S+i] + Tp[5*S+i]) + (Tp[6*S+i] + Tp[7*S+i]));
    ushort_t h = f2bf(s);
    Thi[i] = h;
    Tlo[i] = f2bf(s - bf2f(h));
}

// ---------------- MFMA relation output (in place) --------------------------
// out[r][n] = alpha*( sum_c x[r][c]*Tt[n][c]  -  d_r*U[r][n] ) + x[r][n]
__global__ __launch_bounds__(256) void k_reloutm(
    ushort_t* __restrict__ x, const ushort_t* __restrict__ UT,
    const ushort_t* __restrict__ Thi, const ushort_t* __restrict__ Tlo,
    const float* __restrict__ dvec,
    const void* __restrict__ psi, const void* __restrict__ phi, const void* __restrict__ wr,
    const int* __restrict__ flag)
{
    __shared__ ushort_t xs[16384];   // [c>>3][r][8]  16 KB
    __shared__ ushort_t th[16384];   // [c>>3][n][8]  32 KB
    __shared__ ushort_t tl[16384];
    int t = threadIdx.x;
    size_t row0 = (size_t)blockIdx.x * 64;
    int b = (int)(row0 >> 10);
    int rbase = (int)(row0 & 1023);
    {
        const uint4* src = reinterpret_cast<const uint4*>(x + row0*128);
        #pragma unroll
        for (int c = 0; c < 4; c++){
            int i = t + c*256;
            int r = i >> 4, kg = i & 15;
            *reinterpret_cast<uint4*>(&xs[(kg*64 + r)*8]) = src[i];
        }
        const ushort_t* sh = Thi + (size_t)b*16384;
        const ushort_t* sl = Tlo + (size_t)b*16384;
        #pragma unroll
        for (int c = 0; c < 8; c++){
            int i = t + c*256;                 // n = i>>4, cg = i&15
            int n = i >> 4, cg = i & 15;
            *reinterpret_cast<uint4*>(&th[(cg*128 + n)*8]) =
                *reinterpret_cast<const uint4*>(&sh[n*128 + cg*8]);
            *reinterpret_cast<uint4*>(&tl[(cg*128 + n)*8]) =
                *reinterpret_cast<const uint4*>(&sl[n*128 + cg*8]);
        }
    }
    __syncthreads();
    int f32 = *flag;
    float alpha = ldin(wr,0,f32) * ldin(psi,0,f32) * ldin(phi,0,f32) * (1.f/1024.f);
    int w = t >> 6, lane = t & 63;
    int col = lane & 15, quad = lane >> 4;
    v4f acc[4][2];
    #pragma unroll
    for (int m=0;m<4;m++)
        #pragma unroll
        for (int nt=0;nt<2;nt++) acc[m][nt] = (v4f){0.f,0.f,0.f,0.f};

    #pragma unroll
    for (int kt = 0; kt < 4; kt++){
        int kg = kt*4 + quad;
        v8s a[4], bh[2], bl[2];
        #pragma unroll
        for (int m=0;m<4;m++)
            a[m] = *reinterpret_cast<const v8s*>(&xs[(kg*64 + m*16 + col)*8]);
        #pragma unroll
        for (int nt=0;nt<2;nt++){
            int n = w*32 + nt*16 + col;
            bh[nt] = *reinterpret_cast<const v8s*>(&th[(kg*128 + n)*8]);
            bl[nt] = *reinterpret_cast<const v8s*>(&tl[(kg*128 + n)*8]);
        }
        #pragma unroll
        for (int m=0;m<4;m++)
            #pragma unroll
            for (int nt=0;nt<2;nt++){
                acc[m][nt] = MFMA_BF16(a[m], bh[nt], acc[m][nt], 0, 0, 0);
                acc[m][nt] = MFMA_BF16(a[m], bl[nt], acc[m][nt], 0, 0, 0);
            }
    }
    #pragma unroll
    for (int m=0;m<4;m++){
        float4 d4 = *reinterpret_cast<const float4*>(&dvec[row0 + m*16 + quad*4]);
        #pragma unroll
        for (int nt=0;nt<2;nt++){
            int n = w*32 + nt*16 + col;
            uint2 uu = *reinterpret_cast<const uint2*>(
                &UT[((size_t)b*128 + n)*1024 + rbase + m*16 + quad*4]);
            float uf[4];
            uf[0] = __uint_as_float(uu.x << 16);
            uf[1] = __uint_as_float(uu.x & 0xffff0000u);
            uf[2] = __uint_as_float(uu.y << 16);
            uf[3] = __uint_as_float(uu.y & 0xffff0000u);
            const float* dr = reinterpret_cast<const float*>(&d4);
            #pragma unroll
            for (int reg=0;reg<4;reg++){
                int r = m*16 + quad*4 + reg;
                float xv = bf2f(xs[((n>>3)*64 + r)*8 + (n&7)]);
                float o = fmaf(alpha, acc[m][nt][reg] - dr[reg]*uf[reg], xv);
                x[(row0 + r)*128 + n] = f2bf(o);
            }
        }
    }
}

// ---------------- decoder tail ---------------------------------------------
__global__ __launch_bounds__(256) void k_dec2(
    const bf16* __restrict__ x,           // [B,N,64]
    const float* __restrict__ W2t, const void* __restrict__ b2,
    const float* __restrict__ Wct, const void* __restrict__ bcb,
    const float* __restrict__ Wgt, const void* __restrict__ bgb,
    void* __restrict__ out, const int* __restrict__ flag)
{
    int f32 = *flag;
    __shared__ __align__(16) float w2[64*32];
    __shared__ __align__(16) float wc[32*28];
    __shared__ __align__(16) float wg[32*4];
    __shared__ __align__(16) float xs[8][64];
    __shared__ float hs[8][33];
    size_t row0 = (size_t)blockIdx.x * 8;
    int t = threadIdx.x;
    for (int i=t;i<512;i+=256)  reinterpret_cast<float4*>(w2)[i] = reinterpret_cast<const float4*>(W2t)[i];
    if (t < 224) reinterpret_cast<float4*>(wc)[t] = reinterpret_cast<const float4*>(Wct)[t];
    if (t < 32)  reinterpret_cast<float4*>(wg)[t] = reinterpret_cast<const float4*>(Wgt)[t];
    if (t < 64){
        int row = t >> 3, seg = t & 7;
        uint4 v = *reinterpret_cast<const uint4*>(x + (row0 + row)*64 + seg*8);
        float f[8]; unpack8(v, f);
        *reinterpret_cast<float4*>(&xs[row][seg*8])   = make_float4(f[0],f[1],f[2],f[3]);
        *reinterpret_cast<float4*>(&xs[row][seg*8+4]) = make_float4(f[4],f[5],f[6],f[7]);
    }
    __syncthreads();
    int j = t & 31, r = t >> 5;
    float a = ldin(b2, j, f32);
    #pragma unroll 8
    for (int k=0;k<64;k++) a = fmaf(xs[r][k], w2[k*32 + j], a);
    hs[r][j] = fmaxf(a, 0.f);
    __syncthreads();
    float o;
    if (j < 28){
        o = ldin(bcb, j, f32);
        #pragma unroll
        for (int k=0;k<32;k++) o = fmaf(hs[r][k], wc[k*28 + j], o);
    } else {
        int jj = j - 28;
        o = ldin(bgb, jj, f32);
        #pragma unroll
        for (int k=0;k<32;k++) o = fmaf(hs[r][k], wg[k*4 + jj], o);
    }
    size_t oi = (row0 + r)*32 + j;
    if (f32) ((float*)out)[oi] = o;
    else     ((bf16*)out)[oi] = __float2bfloat16(o);
}

// ---------------------------------------------------------------------------
extern "C" void kernel_launch(void* const* d_in, const int* in_sizes, int n_in,
                              void* d_out, int out_size, void* d_ws, size_t ws_size,
                              hipStream_t stream)
{
    (void)in_sizes; (void)n_in; (void)out_size; (void)ws_size;
    const void* input = d_in[0];
    const void* e1_W = d_in[1];  const void* e1_b = d_in[2];
    const void* bn1_g = d_in[3]; const void* bn1_b = d_in[4];
    const void* e2_W = d_in[5];  const void* e2_b = d_in[6];
    const void* bn2_g = d_in[7]; const void* bn2_b = d_in[8];
    const void* e3_W = d_in[9];  const void* e3_b = d_in[10];
    const void *rW[4], *rb[4], *rpsi[4], *rphi[4], *rwr[4];
    for (int r = 0; r < 4; r++){
        rW[r]   = d_in[11 + r*5 + 0];
        rb[r]   = d_in[11 + r*5 + 1];
        rpsi[r] = d_in[11 + r*5 + 2];
        rphi[r] = d_in[11 + r*5 + 3];
        rwr[r]  = d_in[11 + r*5 + 4];
    }
    const void* d1_W = d_in[31]; const void* d1_b = d_in[32];
    const void* dbn_g = d_in[33];const void* dbn_b = d_in[34];
    const void* d2_W = d_in[35]; const void* d2_b = d_in[36];
    const void* bc_W = d_in[37]; const void* bc_b = d_in[38];
    const void* bg_W = d_in[39]; const void* bg_b = d_in[40];

    // ---- workspace layout (36.2 MB), float offsets ----
    float*    ws_f = (float*)d_ws;
    int*      flag = (int*)d_ws;                        // 64 f reserved
    float*    wpf  = ws_f + 64;                         // 21504 f
    ushort_t* whi  = (ushort_t*)(ws_f + 21568);         // 5*16384 us
    ushort_t* wlo  = (ushort_t*)(ws_f + 62528);         // 5*16384 us
    float*    dd   = ws_f + 103488;                     // 32768 f
    ushort_t* Thi  = (ushort_t*)(ws_f + 136256);        // 524288 us
    ushort_t* Tlo  = (ushort_t*)(ws_f + 398400);        // 524288 us
    float*    Tp   = ws_f + 660544;                     // 4194304 f
    ushort_t* A    = (ushort_t*)(ws_f + 4854848);       // [32768][128] bf16
    ushort_t* UT   = (ushort_t*)(ws_f + 6952000);       // [32][128][1024] bf16
    bf16*     Cenc = (bf16*)A;                          // [32768][64] overlays A
    bf16*     E2   = (bf16*)UT;                         // [32768][128] overlays UT
    bf16*     Cdec = (bf16*)UT;                         // [32768][64] overlays UT

    enum { O_E1=0, O_E2=2048, O_D1=10240, O_D2=18432, O_BC=20480, O_BG=21376 };

    PrepArgs pa;
    const void* srcs[11] = {e1_W, e2_W, d1_W, d2_W, bc_W, bg_W, e3_W, rW[0], rW[1], rW[2], rW[3]};
    const int  Ks[11]   = {32,64,128,64,32,32, 128,128,128,128,128};
    const int  Os[11]   = {64,128,64,32,28,4,  128,128,128,128,128};
    const int  offs[11] = {O_E1,O_E2,O_D1,O_D2,O_BC,O_BG, 0,0,0,0,0};
    for (int i=0;i<11;i++){ pa.w[i]=srcs[i]; pa.K[i]=Ks[i]; pa.O[i]=Os[i]; pa.off[i]=offs[i]; }

    k_detect<<<1, 64, 0, stream>>>(input, flag);
    k_prep<<<dim3(64,11), 256, 0, stream>>>(pa, wpf, whi, wlo, flag);
    k_bnlin<32,64,true><<<512, 128, 0, stream>>>(input, wpf+O_E1, e1_b, bn1_g, bn1_b, Cenc, flag);
    k_bnlin<64,128,false><<<512, 128, 0, stream>>>(Cenc, wpf+O_E2, e2_b, bn2_g, bn2_b, E2, flag);
    k_lin128m<0><<<512, 256, 0, stream>>>((const ushort_t*)E2, whi, wlo, e3_b,
                                          A, (ushort_t*)nullptr, (float*)nullptr, flag);

    for (int r = 0; r < 4; r++){
        const ushort_t* wh = whi + (size_t)(1+r)*16384;
        const ushort_t* wl = wlo + (size_t)(1+r)*16384;
        k_lin128m<1><<<512, 256, 0, stream>>>(A, wh, wl, rb[r],
                                              (ushort_t*)nullptr, UT, dd, flag);
        k_relTm<<<dim3(32,8), 256, 0, stream>>>(A, UT, Tp);
        k_tredm<<<2048, 256, 0, stream>>>(Tp, Thi, Tlo);
        k_reloutm<<<512, 256, 0, stream>>>(A, UT, Thi, Tlo, dd,
                                           rpsi[r], rphi[r], rwr[r], flag);
    }

    k_bnlin<128,64,false><<<512, 128, 0, stream>>>((const bf16*)A, wpf+O_D1, d1_b, dbn_g, dbn_b, Cdec, flag);
    k_dec2<<<4096, 256, 0, stream>>>(Cdec, wpf+O_D2, d2_b, wpf+O_BC, bc_b, wpf+O_BG, bg_b, d_out, flag);
}

// Round 6
// 348.593 us; speedup vs baseline: 2.2310x; 1.0734x over previous
//
#include <hip/hip_runtime.h>
#include <hip/hip_bf16.h>

// ---------------------------------------------------------------------------
// Generator_58737972740271.  R6: MFMA kernels slimmed — B-operands (weights,
// T) live in MFMA-fragment layout in global and are loaded per-fragment into
// registers (L2-resident, coalesced); LDS holds only the 16 KB x-tile.
// Fixes R5's 96 KB LDS over-allocation (1 block/CU -> latency-starved).
// ---------------------------------------------------------------------------

typedef __hip_bfloat16 bf16;
typedef unsigned short ushort_t;
typedef float v4f __attribute__((ext_vector_type(4)));
typedef short v8s __attribute__((ext_vector_type(8)));
#define MFMA_BF16 __builtin_amdgcn_mfma_f32_16x16x32_bf16

#define NB 32
#define NN 1024

__device__ __forceinline__ float ldin(const void* p, size_t i, int f32){
    return f32 ? ((const float*)p)[i] : __bfloat162float(((const bf16*)p)[i]);
}
__device__ __forceinline__ float bf2f(ushort_t u){
    return __uint_as_float((unsigned)u << 16);
}
__device__ __forceinline__ ushort_t f2bf(float v){
    bf16 h = __float2bfloat16(v);
    ushort_t s; __builtin_memcpy(&s, &h, 2);
    return s;
}
__device__ __forceinline__ void unpack8(uint4 v, float* f){
    f[0] = __uint_as_float(v.x << 16);
    f[1] = __uint_as_float(v.x & 0xffff0000u);
    f[2] = __uint_as_float(v.y << 16);
    f[3] = __uint_as_float(v.y & 0xffff0000u);
    f[4] = __uint_as_float(v.z << 16);
    f[5] = __uint_as_float(v.z & 0xffff0000u);
    f[6] = __uint_as_float(v.w << 16);
    f[7] = __uint_as_float(v.w & 0xffff0000u);
}

// ---------------- dtype detector -------------------------------------------
__global__ __launch_bounds__(64) void k_detect(const void* __restrict__ inp, int* __restrict__ flag){
    int t = threadIdx.x;
    unsigned v = ((const unsigned*)inp)[t];
    int hit = (v & 0x80008000u) ? 1 : 0;
    unsigned long long m = __ballot(hit);
    if (t == 0) *flag = (__popcll(m) > 4) ? 1 : 0;   // 1 = fp32 external
}

// ---------------- prep -----------------------------------------------------
// slabs 0..5: fp32 [K][O] transposed weights (bnlin/dec2).
// slabs 6..10: 128x128 weights -> hi/lo bf16, MFMA-B layout [k>>3][n][k&7].
struct PrepArgs {
    const void* w[11];
    int K[11], O[11], off[11];
};

__global__ __launch_bounds__(256) void k_prep(PrepArgs a, float* __restrict__ wpf,
                                              ushort_t* __restrict__ whi, ushort_t* __restrict__ wlo,
                                              const int* __restrict__ flag){
    int f32 = *flag;
    int s = blockIdx.y;
    int idx = blockIdx.x*256 + threadIdx.x;
    if (s < 6){
        int K = a.K[s], O = a.O[s];
        if (idx >= K*O) return;
        int k = idx / O, j = idx - k*O;
        wpf[a.off[s] + idx] = ldin(a.w[s], (size_t)j*K + k, f32);   // W[j,k] -> wt[k][j]
    } else {
        if (idx >= 16384) return;
        int n = idx >> 7, k = idx & 127;
        float v = ldin(a.w[s], (size_t)n*128 + k, f32);
        ushort_t h = f2bf(v);
        ushort_t l = f2bf(v - bf2f(h));
        int di = (s - 6)*16384 + ((k >> 3)*128 + n)*8 + (k & 7);
        whi[di] = h; wlo[di] = l;
    }
}

// ---------------- fused linear + BatchNorm(channel=n) + ReLU (VALU) --------
template<int K, int O, bool EXTIN>
__global__ __launch_bounds__(128) void k_bnlin(
    const void* __restrict__ xin, const float* __restrict__ Wt,
    const void* __restrict__ bias, const void* __restrict__ bng,
    const void* __restrict__ bnb, bf16* __restrict__ out,
    const int* __restrict__ flag)
{
    int f32 = *flag;
    constexpr int BR  = O/16;
    constexpr int NBT = 32/BR;
    constexpr int G   = K/8;
    __shared__ __align__(16) float wt[K*O];
    __shared__ __align__(16) float xst[2][K*36];
    int t = threadIdx.x;
    int w = t >> 6, lane = t & 63;
    int n = blockIdx.x*2 + w;

    for (int i = t; i < K*O/4; i += 128)
        reinterpret_cast<float4*>(wt)[i] = reinterpret_cast<const float4*>(Wt)[i];
    for (int i = lane; i < 32*G; i += 64){
        int b = i / G, g = i - b*G;
        float f[8];
        if (EXTIN && f32){
            const float* src = (const float*)xin + ((size_t)b*NN + n)*K + g*8;
            float4 v0 = *reinterpret_cast<const float4*>(src);
            float4 v1 = *reinterpret_cast<const float4*>(src + 4);
            f[0]=v0.x; f[1]=v0.y; f[2]=v0.z; f[3]=v0.w;
            f[4]=v1.x; f[5]=v1.y; f[6]=v1.z; f[7]=v1.w;
        } else {
            uint4 v = *reinterpret_cast<const uint4*>((const bf16*)xin + ((size_t)b*NN + n)*K + g*8);
            unpack8(v, f);
        }
        #pragma unroll
        for (int j=0;j<8;j++) xst[w][(g*8+j)*36 + b] = f[j];
    }
    __syncthreads();

    int bt = lane % NBT, jt = lane / NBT;
    int b0 = bt*BR, j0 = jt*8;
    const float* xw = xst[w];
    float acc[BR][8];
    #pragma unroll
    for (int i=0;i<BR;i++)
        #pragma unroll
        for (int j=0;j<8;j++) acc[i][j] = 0.f;

    for (int k = 0; k < K; k++){
        float xv[BR], wv[8];
        #pragma unroll
        for (int i=0;i<BR;i+=4)
            *reinterpret_cast<float4*>(&xv[i]) = *reinterpret_cast<const float4*>(&xw[k*36 + b0 + i]);
        *reinterpret_cast<float4*>(&wv[0]) = *reinterpret_cast<const float4*>(&wt[k*O + j0]);
        *reinterpret_cast<float4*>(&wv[4]) = *reinterpret_cast<const float4*>(&wt[k*O + j0 + 4]);
        #pragma unroll
        for (int i=0;i<BR;i++)
            #pragma unroll
            for (int j=0;j<8;j++) acc[i][j] = fmaf(xv[i], wv[j], acc[i][j]);
    }

    float bj[8];
    #pragma unroll
    for (int j=0;j<8;j++) bj[j] = ldin(bias, j0+j, f32);
    float s1 = 0.f, s2 = 0.f;
    #pragma unroll
    for (int i=0;i<BR;i++)
        #pragma unroll
        for (int j=0;j<8;j++){
            float a = acc[i][j] + bj[j];
            acc[i][j] = a; s1 += a; s2 = fmaf(a, a, s2);
        }
    #pragma unroll
    for (int off = 32; off > 0; off >>= 1){
        s1 += __shfl_down(s1, off);
        s2 += __shfl_down(s2, off);
    }
    s1 = __shfl(s1, 0); s2 = __shfl(s2, 0);
    const float M = 32.f * O;
    float m  = s1 / M;
    float vv = s2 / M - m*m;
    float rs = rsqrtf(vv + 1e-5f);
    float gv = ldin(bng, n, f32), bv = ldin(bnb, n, f32);
    #pragma unroll
    for (int i=0;i<BR;i++){
        union { uint4 u; ushort_t s[8]; } pk;
        #pragma unroll
        for (int j=0;j<8;j++)
            pk.s[j] = f2bf(fmaxf(fmaf(gv*(acc[i][j]-m), rs, bv), 0.f));
        *reinterpret_cast<uint4*>(out + ((size_t)(b0+i)*NN + n)*O + j0) = pk.u;
    }
}

// ---------------- MFMA 128->128 linear -------------------------------------
// block = 64 rows x 128 cols, 4 waves (wave = 64r x 32n).  W hi/lo bf16 read
// per-fragment from global (MFMA-B layout, L2-resident).  LDS: 16 KB x-tile.
// MODE 0: sigmoid -> outA row-major.  MODE 1: relu -> outUT [b][n][r] + dvec.
template<int MODE>
__global__ __launch_bounds__(256) void k_lin128m(
    const ushort_t* __restrict__ xin,                    // row-major [32768][128]
    const ushort_t* __restrict__ Whi, const ushort_t* __restrict__ Wlo,
    const void* __restrict__ bias,
    ushort_t* __restrict__ outA, ushort_t* __restrict__ outUT,
    float* __restrict__ dvec, const int* __restrict__ flag)
{
    __shared__ ushort_t xs[8192];    // [k>>3][r(64)][8]  16 KB
    int t = threadIdx.x;
    size_t row0 = (size_t)blockIdx.x * 64;
    {
        const uint4* src = reinterpret_cast<const uint4*>(xin + row0*128);
        #pragma unroll
        for (int c = 0; c < 4; c++){
            int i = t + c*256;
            int r = i >> 4, kg = i & 15;
            *reinterpret_cast<uint4*>(&xs[(kg*64 + r)*8]) = src[i];
        }
    }
    __syncthreads();
    int w = t >> 6, lane = t & 63;
    int col = lane & 15, quad = lane >> 4;
    v4f acc[4][2];
    #pragma unroll
    for (int m=0;m<4;m++)
        #pragma unroll
        for (int nt=0;nt<2;nt++) acc[m][nt] = (v4f){0.f,0.f,0.f,0.f};

    #pragma unroll
    for (int kt = 0; kt < 4; kt++){
        int kg = kt*4 + quad;
        v8s a[4], bh[2], bl[2];
        #pragma unroll
        for (int nt=0;nt<2;nt++){
            int n = w*32 + nt*16 + col;
            bh[nt] = *reinterpret_cast<const v8s*>(&Whi[(kg*128 + n)*8]);
            bl[nt] = *reinterpret_cast<const v8s*>(&Wlo[(kg*128 + n)*8]);
        }
        #pragma unroll
        for (int m=0;m<4;m++)
            a[m] = *reinterpret_cast<const v8s*>(&xs[(kg*64 + m*16 + col)*8]);
        #pragma unroll
        for (int m=0;m<4;m++)
            #pragma unroll
            for (int nt=0;nt<2;nt++){
                acc[m][nt] = MFMA_BF16(a[m], bh[nt], acc[m][nt], 0, 0, 0);
                acc[m][nt] = MFMA_BF16(a[m], bl[nt], acc[m][nt], 0, 0, 0);
            }
    }
    int f32 = *flag;
    int b = (int)(row0 >> 10);
    int rbase = (int)(row0 & 1023);
    #pragma unroll
    for (int nt=0;nt<2;nt++){
        int n = w*32 + nt*16 + col;
        float bn = ldin(bias, n, f32);
        #pragma unroll
        for (int m=0;m<4;m++){
            if (MODE == 0){
                #pragma unroll
                for (int reg=0;reg<4;reg++){
                    int r = m*16 + quad*4 + reg;
                    float v = acc[m][nt][reg] + bn;
                    outA[(row0 + r)*128 + n] = f2bf(1.f/(1.f+expf(-v)));
                }
            } else {
                union { uint2 u; ushort_t s[4]; } pk;
                #pragma unroll
                for (int reg=0;reg<4;reg++)
                    pk.s[reg] = f2bf(fmaxf(acc[m][nt][reg] + bn, 0.f));
                int rb = rbase + m*16 + quad*4;
                *reinterpret_cast<uint2*>(&outUT[((size_t)b*128 + n)*1024 + rb]) = pk.u;
            }
        }
    }
    if (MODE == 1 && t < 64){
        float s = 0.f;
        #pragma unroll 8
        for (int k=0;k<128;k++){
            float v = bf2f(xs[((k>>3)*64 + t)*8 + (k&7)]);
            s = fmaf(v, v, s);
        }
        dvec[row0 + t] = s;
    }
}

// ---------------- MFMA  Tt = U^T x,  split-K x8 ----------------------------
// grid (32 b, 8 rs).  A-fragments (U^T) read straight from UT global;
// B (x^T) scatter-staged in 16 KB LDS.
__global__ __launch_bounds__(256) void k_relTm(
    const ushort_t* __restrict__ x,   // row-major [32768][128]
    const ushort_t* __restrict__ UT,  // [32][128][1024]
    float* __restrict__ Tp)           // [8][32][128][128]
{
    __shared__ ushort_t xts[8192];    // [r>>3][c][8]  16 KB
    int b = blockIdx.x, rs = blockIdx.y;
    int t = threadIdx.x;
    int w = t >> 6, lane = t & 63;
    int col = lane & 15, quad = lane >> 4;
    int wn = (w >> 1)*64, wc = (w & 1)*64;
    const ushort_t* utb = UT + ((size_t)b << 17);
    v4f acc[4][4];
    #pragma unroll
    for (int m=0;m<4;m++)
        #pragma unroll
        for (int q=0;q<4;q++) acc[m][q] = (v4f){0.f,0.f,0.f,0.f};

    for (int ch = 0; ch < 2; ch++){
        __syncthreads();
        int r0 = rs*128 + ch*64;
        #pragma unroll
        for (int c = 0; c < 4; c++){           // x scatter-transpose
            int i = t + c*256;
            int r = i >> 4, cs8 = (i & 15)*8;
            uint4 v = *reinterpret_cast<const uint4*>(&x[((size_t)b*1024 + r0 + r)*128 + cs8]);
            int base = ((r >> 3)*128 + cs8)*8 + (r & 7);
            xts[base     ] = (ushort_t)(v.x & 0xffff);
            xts[base + 8 ] = (ushort_t)(v.x >> 16);
            xts[base + 16] = (ushort_t)(v.y & 0xffff);
            xts[base + 24] = (ushort_t)(v.y >> 16);
            xts[base + 32] = (ushort_t)(v.z & 0xffff);
            xts[base + 40] = (ushort_t)(v.z >> 16);
            xts[base + 48] = (ushort_t)(v.w & 0xffff);
            xts[base + 56] = (ushort_t)(v.w >> 16);
        }
        __syncthreads();
        #pragma unroll
        for (int kt = 0; kt < 2; kt++){
            int kg = kt*4 + quad;
            v8s a[4], bb[4];
            #pragma unroll
            for (int m=0;m<4;m++)
                a[m] = *reinterpret_cast<const v8s*>(
                    &utb[((size_t)(wn + m*16 + col))*1024 + r0 + kg*8]);
            #pragma unroll
            for (int q=0;q<4;q++)
                bb[q] = *reinterpret_cast<const v8s*>(&xts[(kg*128 + wc + q*16 + col)*8]);
            #pragma unroll
            for (int m=0;m<4;m++)
                #pragma unroll
                for (int q=0;q<4;q++)
                    acc[m][q] = MFMA_BF16(a[m], bb[q], acc[m][q], 0, 0, 0);
        }
    }
    float* dst = Tp + (((size_t)rs*NB + b) << 14);
    #pragma unroll
    for (int m=0;m<4;m++)
        #pragma unroll
        for (int q=0;q<4;q++)
            #pragma unroll
            for (int reg=0;reg<4;reg++){
                int n = wn + m*16 + quad*4 + reg;
                int c = wc + q*16 + col;
                dst[n*128 + c] = acc[m][q][reg];
            }
}

// ---------------- reduce partials -> Tt hi/lo bf16 in MFMA-B layout --------
__global__ __launch_bounds__(256) void k_tredm(const float* __restrict__ Tp,
                                               ushort_t* __restrict__ Thi, ushort_t* __restrict__ Tlo){
    int i = blockIdx.x*256 + threadIdx.x;        // 524288 total
    const size_t S = 524288;
    float s = ((Tp[i] + Tp[S+i]) + (Tp[2*S+i] + Tp[3*S+i]))
            + ((Tp[4*S+i] + Tp[5*S+i]) + (Tp[6*S+i] + Tp[7*S+i]));
    int bb = i >> 14, j = i & 16383;
    int n = j >> 7, c = j & 127;
    int di = (bb << 14) + ((c >> 3)*128 + n)*8 + (c & 7);
    ushort_t h = f2bf(s);
    Thi[di] = h;
    Tlo[di] = f2bf(s - bf2f(h));
}

// ---------------- MFMA relation output (in place) --------------------------
// out[r][n] = alpha*( sum_c x[r][c]*Tt[n][c]  -  d_r*U[r][n] ) + x[r][n]
// T hi/lo fragments read straight from global (B layout).  LDS: 16 KB x.
__global__ __launch_bounds__(256) void k_reloutm(
    ushort_t* __restrict__ x, const ushort_t* __restrict__ UT,
    const ushort_t* __restrict__ Thi, const ushort_t* __restrict__ Tlo,
    const float* __restrict__ dvec,
    const void* __restrict__ psi, const void* __restrict__ phi, const void* __restrict__ wr,
    const int* __restrict__ flag)
{
    __shared__ ushort_t xs[8192];    // [c>>3][r(64)][8]  16 KB
    int t = threadIdx.x;
    size_t row0 = (size_t)blockIdx.x * 64;
    int b = (int)(row0 >> 10);
    int rbase = (int)(row0 & 1023);
    {
        const uint4* src = reinterpret_cast<const uint4*>(x + row0*128);
        #pragma unroll
        for (int c = 0; c < 4; c++){
            int i = t + c*256;
            int r = i >> 4, kg = i & 15;
            *reinterpret_cast<uint4*>(&xs[(kg*64 + r)*8]) = src[i];
        }
    }
    __syncthreads();
    int f32 = *flag;
    float alpha = ldin(wr,0,f32) * ldin(psi,0,f32) * ldin(phi,0,f32) * (1.f/1024.f);
    int w = t >> 6, lane = t & 63;
    int col = lane & 15, quad = lane >> 4;
    const ushort_t* sh = Thi + ((size_t)b << 14);
    const ushort_t* sl = Tlo + ((size_t)b << 14);
    v4f acc[4][2];
    #pragma unroll
    for (int m=0;m<4;m++)
        #pragma unroll
        for (int nt=0;nt<2;nt++) acc[m][nt] = (v4f){0.f,0.f,0.f,0.f};

    #pragma unroll
    for (int kt = 0; kt < 4; kt++){
        int kg = kt*4 + quad;
        v8s a[4], bh[2], bl[2];
        #pragma unroll
        for (int nt=0;nt<2;nt++){
            int n = w*32 + nt*16 + col;
            bh[nt] = *reinterpret_cast<const v8s*>(&sh[(kg*128 + n)*8]);
            bl[nt] = *reinterpret_cast<const v8s*>(&sl[(kg*128 + n)*8]);
        }
        #pragma unroll
        for (int m=0;m<4;m++)
            a[m] = *reinterpret_cast<const v8s*>(&xs[(kg*64 + m*16 + col)*8]);
        #pragma unroll
        for (int m=0;m<4;m++)
            #pragma unroll
            for (int nt=0;nt<2;nt++){
                acc[m][nt] = MFMA_BF16(a[m], bh[nt], acc[m][nt], 0, 0, 0);
                acc[m][nt] = MFMA_BF16(a[m], bl[nt], acc[m][nt], 0, 0, 0);
            }
    }
    #pragma unroll
    for (int m=0;m<4;m++){
        float4 d4 = *reinterpret_cast<const float4*>(&dvec[row0 + m*16 + quad*4]);
        #pragma unroll
        for (int nt=0;nt<2;nt++){
            int n = w*32 + nt*16 + col;
            uint2 uu = *reinterpret_cast<const uint2*>(
                &UT[((size_t)b*128 + n)*1024 + rbase + m*16 + quad*4]);
            float uf[4];
            uf[0] = __uint_as_float(uu.x << 16);
            uf[1] = __uint_as_float(uu.x & 0xffff0000u);
            uf[2] = __uint_as_float(uu.y << 16);
            uf[3] = __uint_as_float(uu.y & 0xffff0000u);
            const float* dr = reinterpret_cast<const float*>(&d4);
            #pragma unroll
            for (int reg=0;reg<4;reg++){
                int r = m*16 + quad*4 + reg;
                float xv = bf2f(xs[((n>>3)*64 + r)*8 + (n&7)]);
                float o = fmaf(alpha, acc[m][nt][reg] - dr[reg]*uf[reg], xv);
                x[(row0 + r)*128 + n] = f2bf(o);
            }
        }
    }
}

// ---------------- decoder tail ---------------------------------------------
__global__ __launch_bounds__(256) void k_dec2(
    const bf16* __restrict__ x,           // [B,N,64]
    const float* __restrict__ W2t, const void* __restrict__ b2,
    const float* __restrict__ Wct, const void* __restrict__ bcb,
    const float* __restrict__ Wgt, const void* __restrict__ bgb,
    void* __restrict__ out, const int* __restrict__ flag)
{
    int f32 = *flag;
    __shared__ __align__(16) float w2[64*32];
    __shared__ __align__(16) float wc[32*28];
    __shared__ __align__(16) float wg[32*4];
    __shared__ __align__(16) float xs[8][64];
    __shared__ float hs[8][33];
    size_t row0 = (size_t)blockIdx.x * 8;
    int t = threadIdx.x;
    for (int i=t;i<512;i+=256)  reinterpret_cast<float4*>(w2)[i] = reinterpret_cast<const float4*>(W2t)[i];
    if (t < 224) reinterpret_cast<float4*>(wc)[t] = reinterpret_cast<const float4*>(Wct)[t];
    if (t < 32)  reinterpret_cast<float4*>(wg)[t] = reinterpret_cast<const float4*>(Wgt)[t];
    if (t < 64){
        int row = t >> 3, seg = t & 7;
        uint4 v = *reinterpret_cast<const uint4*>(x + (row0 + row)*64 + seg*8);
        float f[8]; unpack8(v, f);
        *reinterpret_cast<float4*>(&xs[row][seg*8])   = make_float4(f[0],f[1],f[2],f[3]);
        *reinterpret_cast<float4*>(&xs[row][seg*8+4]) = make_float4(f[4],f[5],f[6],f[7]);
    }
    __syncthreads();
    int j = t & 31, r = t >> 5;
    float a = ldin(b2, j, f32);
    #pragma unroll 8
    for (int k=0;k<64;k++) a = fmaf(xs[r][k], w2[k*32 + j], a);
    hs[r][j] = fmaxf(a, 0.f);
    __syncthreads();
    float o;
    if (j < 28){
        o = ldin(bcb, j, f32);
        #pragma unroll
        for (int k=0;k<32;k++) o = fmaf(hs[r][k], wc[k*28 + j], o);
    } else {
        int jj = j - 28;
        o = ldin(bgb, jj, f32);
        #pragma unroll
        for (int k=0;k<32;k++) o = fmaf(hs[r][k], wg[k*4 + jj], o);
    }
    size_t oi = (row0 + r)*32 + j;
    if (f32) ((float*)out)[oi] = o;
    else     ((bf16*)out)[oi] = __float2bfloat16(o);
}

// ---------------------------------------------------------------------------
extern "C" void kernel_launch(void* const* d_in, const int* in_sizes, int n_in,
                              void* d_out, int out_size, void* d_ws, size_t ws_size,
                              hipStream_t stream)
{
    (void)in_sizes; (void)n_in; (void)out_size; (void)ws_size;
    const void* input = d_in[0];
    const void* e1_W = d_in[1];  const void* e1_b = d_in[2];
    const void* bn1_g = d_in[3]; const void* bn1_b = d_in[4];
    const void* e2_W = d_in[5];  const void* e2_b = d_in[6];
    const void* bn2_g = d_in[7]; const void* bn2_b = d_in[8];
    const void* e3_W = d_in[9];  const void* e3_b = d_in[10];
    const void *rW[4], *rb[4], *rpsi[4], *rphi[4], *rwr[4];
    for (int r = 0; r < 4; r++){
        rW[r]   = d_in[11 + r*5 + 0];
        rb[r]   = d_in[11 + r*5 + 1];
        rpsi[r] = d_in[11 + r*5 + 2];
        rphi[r] = d_in[11 + r*5 + 3];
        rwr[r]  = d_in[11 + r*5 + 4];
    }
    const void* d1_W = d_in[31]; const void* d1_b = d_in[32];
    const void* dbn_g = d_in[33];const void* dbn_b = d_in[34];
    const void* d2_W = d_in[35]; const void* d2_b = d_in[36];
    const void* bc_W = d_in[37]; const void* bc_b = d_in[38];
    const void* bg_W = d_in[39]; const void* bg_b = d_in[40];

    // ---- workspace layout (36.2 MB), float offsets ----
    float*    ws_f = (float*)d_ws;
    int*      flag = (int*)d_ws;                        // 64 f reserved
    float*    wpf  = ws_f + 64;                         // 21504 f
    ushort_t* whi  = (ushort_t*)(ws_f + 21568);         // 5*16384 us
    ushort_t* wlo  = (ushort_t*)(ws_f + 62528);         // 5*16384 us
    float*    dd   = ws_f + 103488;                     // 32768 f
    ushort_t* Thi  = (ushort_t*)(ws_f + 136256);        // 524288 us
    ushort_t* Tlo  = (ushort_t*)(ws_f + 398400);        // 524288 us
    float*    Tp   = ws_f + 660544;                     // 4194304 f
    ushort_t* A    = (ushort_t*)(ws_f + 4854848);       // [32768][128] bf16
    ushort_t* UT   = (ushort_t*)(ws_f + 6952000);       // [32][128][1024] bf16
    bf16*     Cenc = (bf16*)A;                          // [32768][64] overlays A
    bf16*     E2   = (bf16*)UT;                         // [32768][128] overlays UT
    bf16*     Cdec = (bf16*)UT;                         // [32768][64] overlays UT

    enum { O_E1=0, O_E2=2048, O_D1=10240, O_D2=18432, O_BC=20480, O_BG=21376 };

    PrepArgs pa;
    const void* srcs[11] = {e1_W, e2_W, d1_W, d2_W, bc_W, bg_W, e3_W, rW[0], rW[1], rW[2], rW[3]};
    const int  Ks[11]   = {32,64,128,64,32,32, 128,128,128,128,128};
    const int  Os[11]   = {64,128,64,32,28,4,  128,128,128,128,128};
    const int  offs[11] = {O_E1,O_E2,O_D1,O_D2,O_BC,O_BG, 0,0,0,0,0};
    for (int i=0;i<11;i++){ pa.w[i]=srcs[i]; pa.K[i]=Ks[i]; pa.O[i]=Os[i]; pa.off[i]=offs[i]; }

    k_detect<<<1, 64, 0, stream>>>(input, flag);
    k_prep<<<dim3(64,11), 256, 0, stream>>>(pa, wpf, whi, wlo, flag);
    k_bnlin<32,64,true><<<512, 128, 0, stream>>>(input, wpf+O_E1, e1_b, bn1_g, bn1_b, Cenc, flag);
    k_bnlin<64,128,false><<<512, 128, 0, stream>>>(Cenc, wpf+O_E2, e2_b, bn2_g, bn2_b, E2, flag);
    k_lin128m<0><<<512, 256, 0, stream>>>((const ushort_t*)E2, whi, wlo, e3_b,
                                          A, (ushort_t*)nullptr, (float*)nullptr, flag);

    for (int r = 0; r < 4; r++){
        const ushort_t* wh = whi + (size_t)(1+r)*16384;
        const ushort_t* wl = wlo + (size_t)(1+r)*16384;
        k_lin128m<1><<<512, 256, 0, stream>>>(A, wh, wl, rb[r],
                                              (ushort_t*)nullptr, UT, dd, flag);
        k_relTm<<<dim3(32,8), 256, 0, stream>>>(A, UT, Tp);
        k_tredm<<<2048, 256, 0, stream>>>(Tp, Thi, Tlo);
        k_reloutm<<<512, 256, 0, stream>>>(A, UT, Thi, Tlo, dd,
                                           rpsi[r], rphi[r], rwr[r], flag);
    }

    k_bnlin<128,64,false><<<512, 128, 0, stream>>>((const bf16*)A, wpf+O_D1, d1_b, dbn_g, dbn_b, Cdec, flag);
    k_dec2<<<4096, 256, 0, stream>>>(Cdec, wpf+O_D2, d2_b, wpf+O_BC, bc_b, wpf+O_BG, bg_b, d_out, flag);
}